// Round 1
// baseline (2200.978 us; speedup 1.0000x reference)
//
#include <hip/hip_runtime.h>
#include <math.h>

// B=2, T=2048, E=1024, H=16, HS=64
// Workspace layout (floats):
//   Wqkv : 3,145,728   (E x 3072 repacked QKV weights)
//   h    : 4,194,304   (LN1 out; reused as h2 for LN2 out)
//   QKV  : 12,582,912  (4096 x 3072)
//   Obuf : 4,194,304   (attention out, [B,T,H*HS])
//   x1   : 4,194,304   (residual-1 result)
//   f    = QKV (overlap, 16,777,216 floats = QKV+Obuf exactly) for FFN hidden
// Total: 113.25 MB

// ---------------- repack Wq|Wk|Wv [H,E,HS] -> Wqkv [E, 3*H*HS] ----------------
__global__ __launch_bounds__(256) void repack_qkv(
    const float* __restrict__ Wq, const float* __restrict__ Wk,
    const float* __restrict__ Wv, float* __restrict__ out) {
  int idx = blockIdx.x * 256 + threadIdx.x;
  if (idx >= 3072 * 1024) return;
  int n = idx % 3072, e = idx / 3072;
  int mat = n >> 10, hd = n & 1023;
  int h = hd >> 6, d = hd & 63;
  const float* W = (mat == 0) ? Wq : (mat == 1 ? Wk : Wv);
  out[idx] = W[((size_t)(h << 10) + e) * 64 + d];  // W[h,e,d] = h*E*HS + e*HS + d
}

// ---------------- LayerNorm over rows of 1024 ----------------
__global__ __launch_bounds__(256) void ln_kernel(
    const float* __restrict__ x, const float* __restrict__ g,
    const float* __restrict__ b, float* __restrict__ out) {
  int row = blockIdx.x;
  const float* xr = x + (size_t)row * 1024;
  int t = threadIdx.x;
  float4 v = *(const float4*)(xr + t * 4);
  float s = v.x + v.y + v.z + v.w;
  float q = v.x * v.x + v.y * v.y + v.z * v.z + v.w * v.w;
  #pragma unroll
  for (int off = 32; off >= 1; off >>= 1) {
    s += __shfl_xor(s, off);
    q += __shfl_xor(q, off);
  }
  __shared__ float ss[4], qq[4];
  int wid = t >> 6;
  if ((t & 63) == 0) { ss[wid] = s; qq[wid] = q; }
  __syncthreads();
  float st = ss[0] + ss[1] + ss[2] + ss[3];
  float qt = qq[0] + qq[1] + qq[2] + qq[3];
  float mean = st * (1.0f / 1024.0f);
  float var = qt * (1.0f / 1024.0f) - mean * mean;
  float rstd = rsqrtf(var + 1e-5f);
  float4 gv = *(const float4*)(g + t * 4);
  float4 bv = *(const float4*)(b + t * 4);
  float4 o;
  o.x = (v.x - mean) * rstd * gv.x + bv.x;
  o.y = (v.y - mean) * rstd * gv.y + bv.y;
  o.z = (v.z - mean) * rstd * gv.z + bv.z;
  o.w = (v.w - mean) * rstd * gv.w + bv.w;
  *(float4*)(out + (size_t)row * 1024 + t * 4) = o;
}

// ---------------- fp32 tiled GEMM: C = A[MxK] @ B[KxN] (+bias +res, relu) ----
// 64x64 tile, BK=16, 256 threads, 4x4 microtile per thread
__global__ __launch_bounds__(256) void gemm_f32(
    const float* __restrict__ A, const float* __restrict__ B,
    const float* __restrict__ bias, const float* __restrict__ res,
    float* __restrict__ C, int M, int N, int K, int relu) {
  __shared__ float As[16][68];  // stored transposed: As[k][m], stride 68 keeps 16B align
  __shared__ float Bs[16][68];
  int t = threadIdx.x;
  int tx = t & 15, ty = t >> 4;
  int bm = blockIdx.y * 64, bn = blockIdx.x * 64;
  float acc[4][4] = {};
  int m_a = t >> 2, k_a = (t & 3) << 2;
  int k_b = t >> 4, n_b = tx << 2;
  const float* Aptr = A + (size_t)(bm + m_a) * K + k_a;
  const float* Bptr = B + (size_t)k_b * N + bn + n_b;
  for (int k0 = 0; k0 < K; k0 += 16) {
    float4 av = *(const float4*)(Aptr + k0);
    float4 bv = *(const float4*)(Bptr + (size_t)k0 * N);
    As[k_a + 0][m_a] = av.x;
    As[k_a + 1][m_a] = av.y;
    As[k_a + 2][m_a] = av.z;
    As[k_a + 3][m_a] = av.w;
    *(float4*)&Bs[k_b][n_b] = bv;
    __syncthreads();
    #pragma unroll
    for (int k = 0; k < 16; ++k) {
      float4 a4 = *(const float4*)&As[k][ty << 2];
      float4 b4 = *(const float4*)&Bs[k][tx << 2];
      float a[4] = {a4.x, a4.y, a4.z, a4.w};
      float b[4] = {b4.x, b4.y, b4.z, b4.w};
      #pragma unroll
      for (int i = 0; i < 4; ++i)
        #pragma unroll
        for (int j = 0; j < 4; ++j) acc[i][j] = fmaf(a[i], b[j], acc[i][j]);
    }
    __syncthreads();
  }
  float4 bb = make_float4(0.f, 0.f, 0.f, 0.f);
  if (bias) bb = *(const float4*)(bias + bn + (tx << 2));
  #pragma unroll
  for (int i = 0; i < 4; ++i) {
    int m = bm + (ty << 2) + i;
    float4 rv = make_float4(0.f, 0.f, 0.f, 0.f);
    if (res) rv = *(const float4*)(res + (size_t)m * N + bn + (tx << 2));
    float4 o;
    o.x = acc[i][0] + bb.x + rv.x;
    o.y = acc[i][1] + bb.y + rv.y;
    o.z = acc[i][2] + bb.z + rv.z;
    o.w = acc[i][3] + bb.w + rv.w;
    if (relu) {
      o.x = fmaxf(o.x, 0.f); o.y = fmaxf(o.y, 0.f);
      o.z = fmaxf(o.z, 0.f); o.w = fmaxf(o.w, 0.f);
    }
    *(float4*)(C + (size_t)m * N + bn + (tx << 2)) = o;
  }
}

// ---------------- flash attention fp32, 64-row Q tiles ----------------
// grid (qt=32, bh=32), block 256. QKV rows: [Q(1024) | K(1024) | V(1024)]
__global__ __launch_bounds__(256) void attn_kernel(
    const float* __restrict__ QKV, float* __restrict__ O) {
  __shared__ float Qs[64][65];
  __shared__ float Ks[64][65];
  __shared__ float Vs[64][65];
  __shared__ float Ps[64][65];
  __shared__ float mS[64], lS[64];
  const int T = 2048;
  int qt = blockIdx.x, bh = blockIdx.y;
  int b = bh >> 4, h = bh & 15;
  int t = threadIdx.x;
  int tx = t & 15, ty = t >> 4;
  const float scale = 0.125f;  // HS^-0.5
  {
    int r = t >> 2, c0 = (t & 3) << 4;
    const float* src = QKV + (size_t)(b * T + (qt << 6) + r) * 3072 + (h << 6) + c0;
    #pragma unroll
    for (int c = 0; c < 16; c += 4) {
      float4 v = *(const float4*)(src + c);
      Qs[r][c0 + c] = v.x; Qs[r][c0 + c + 1] = v.y;
      Qs[r][c0 + c + 2] = v.z; Qs[r][c0 + c + 3] = v.w;
    }
  }
  if (t < 64) { mS[t] = -1e30f; lS[t] = 0.f; }
  float o[4][4] = {};
  __syncthreads();
  for (int kt = 0; kt <= qt; ++kt) {
    {
      int r = t >> 2, c0 = (t & 3) << 4;
      const float* kp = QKV + (size_t)(b * T + (kt << 6) + r) * 3072 + 1024 + (h << 6) + c0;
      #pragma unroll
      for (int c = 0; c < 16; c += 4) {
        float4 v = *(const float4*)(kp + c);
        Ks[r][c0 + c] = v.x; Ks[r][c0 + c + 1] = v.y;
        Ks[r][c0 + c + 2] = v.z; Ks[r][c0 + c + 3] = v.w;
        float4 w = *(const float4*)(kp + 1024 + c);
        Vs[r][c0 + c] = w.x; Vs[r][c0 + c + 1] = w.y;
        Vs[r][c0 + c + 2] = w.z; Vs[r][c0 + c + 3] = w.w;
      }
    }
    __syncthreads();
    // S = scale * Q @ K^T  (4x4 per thread)
    float s[4][4] = {};
    #pragma unroll 4
    for (int d = 0; d < 64; ++d) {
      float qv[4], kv[4];
      #pragma unroll
      for (int i = 0; i < 4; ++i) qv[i] = Qs[(ty << 2) + i][d];
      #pragma unroll
      for (int j = 0; j < 4; ++j) kv[j] = Ks[(tx << 2) + j][d];
      #pragma unroll
      for (int i = 0; i < 4; ++i)
        #pragma unroll
        for (int j = 0; j < 4; ++j) s[i][j] = fmaf(qv[i], kv[j], s[i][j]);
    }
    bool diag = (kt == qt);
    float alpha[4];
    #pragma unroll
    for (int i = 0; i < 4; ++i) {
      int r = (ty << 2) + i;
      #pragma unroll
      for (int j = 0; j < 4; ++j) {
        float sv = s[i][j] * scale;
        if (diag && ((tx << 2) + j > r)) sv = -1e30f;
        s[i][j] = sv;
      }
      float mx = fmaxf(fmaxf(s[i][0], s[i][1]), fmaxf(s[i][2], s[i][3]));
      mx = fmaxf(mx, __shfl_xor(mx, 1, 16));
      mx = fmaxf(mx, __shfl_xor(mx, 2, 16));
      mx = fmaxf(mx, __shfl_xor(mx, 4, 16));
      mx = fmaxf(mx, __shfl_xor(mx, 8, 16));
      float mold = mS[r];
      float mnew = fmaxf(mold, mx);
      float rs = 0.f;
      #pragma unroll
      for (int j = 0; j < 4; ++j) {
        float p = __expf(s[i][j] - mnew);
        s[i][j] = p;
        rs += p;
      }
      rs += __shfl_xor(rs, 1, 16);
      rs += __shfl_xor(rs, 2, 16);
      rs += __shfl_xor(rs, 4, 16);
      rs += __shfl_xor(rs, 8, 16);
      alpha[i] = __expf(mold - mnew);
      if (tx == 0) {
        mS[r] = mnew;
        lS[r] = alpha[i] * lS[r] + rs;
      }
      Ps[r][(tx << 2) + 0] = s[i][0];
      Ps[r][(tx << 2) + 1] = s[i][1];
      Ps[r][(tx << 2) + 2] = s[i][2];
      Ps[r][(tx << 2) + 3] = s[i][3];
    }
    __syncthreads();
    // O = O*alpha + P @ V
    #pragma unroll
    for (int i = 0; i < 4; ++i)
      #pragma unroll
      for (int j = 0; j < 4; ++j) o[i][j] *= alpha[i];
    #pragma unroll 4
    for (int k = 0; k < 64; ++k) {
      float pv[4], vv[4];
      #pragma unroll
      for (int i = 0; i < 4; ++i) pv[i] = Ps[(ty << 2) + i][k];
      #pragma unroll
      for (int j = 0; j < 4; ++j) vv[j] = Vs[k][(tx << 2) + j];
      #pragma unroll
      for (int i = 0; i < 4; ++i)
        #pragma unroll
        for (int j = 0; j < 4; ++j) o[i][j] = fmaf(pv[i], vv[j], o[i][j]);
    }
    __syncthreads();
  }
  #pragma unroll
  for (int i = 0; i < 4; ++i) {
    int r = (ty << 2) + i;
    float linv = 1.0f / lS[r];
    float4 ov;
    ov.x = o[i][0] * linv;
    ov.y = o[i][1] * linv;
    ov.z = o[i][2] * linv;
    ov.w = o[i][3] * linv;
    *(float4*)(O + (size_t)(b * T + (qt << 6) + r) * 1024 + (h << 6) + (tx << 2)) = ov;
  }
}

extern "C" void kernel_launch(void* const* d_in, const int* in_sizes, int n_in,
                              void* d_out, int out_size, void* d_ws, size_t ws_size,
                              hipStream_t stream) {
  const float* x   = (const float*)d_in[0];
  const float* Wq  = (const float*)d_in[1];
  const float* Wk  = (const float*)d_in[2];
  const float* Wv  = (const float*)d_in[3];
  const float* Wp  = (const float*)d_in[4];
  const float* bp  = (const float*)d_in[5];
  const float* W1  = (const float*)d_in[6];
  const float* b1  = (const float*)d_in[7];
  const float* W2  = (const float*)d_in[8];
  const float* b2  = (const float*)d_in[9];
  const float* g1  = (const float*)d_in[10];
  const float* be1 = (const float*)d_in[11];
  const float* g2  = (const float*)d_in[12];
  const float* be2 = (const float*)d_in[13];
  float* out = (float*)d_out;

  float* ws   = (float*)d_ws;
  float* Wqkv = ws;                   // 3,145,728
  float* h    = Wqkv + 3145728;       // 4,194,304
  float* QKV  = h + 4194304;          // 12,582,912
  float* Obuf = QKV + 12582912;       // 4,194,304
  float* x1   = Obuf + 4194304;       // 4,194,304
  float* f    = QKV;                  // 16,777,216 (overlaps dead QKV+Obuf)
  float* h2   = h;                    // reuse (h dead after QKV GEMM)

  repack_qkv<<<12288, 256, 0, stream>>>(Wq, Wk, Wv, Wqkv);
  ln_kernel<<<4096, 256, 0, stream>>>(x, g1, be1, h);
  gemm_f32<<<dim3(48, 64), 256, 0, stream>>>(h, Wqkv, nullptr, nullptr, QKV,
                                             4096, 3072, 1024, 0);
  attn_kernel<<<dim3(32, 32), 256, 0, stream>>>(QKV, Obuf);
  gemm_f32<<<dim3(16, 64), 256, 0, stream>>>(Obuf, Wp, bp, x, x1,
                                             4096, 1024, 1024, 0);
  ln_kernel<<<4096, 256, 0, stream>>>(x1, g2, be2, h2);
  gemm_f32<<<dim3(64, 64), 256, 0, stream>>>(h2, W1, b1, nullptr, f,
                                             4096, 4096, 1024, 1);
  gemm_f32<<<dim3(16, 64), 256, 0, stream>>>(f, W2, b2, x1, out,
                                             4096, 1024, 4096, 0);
}

// Round 2
// 547.051 us; speedup vs baseline: 4.0234x; 4.0234x over previous
//
#include <hip/hip_runtime.h>
#include <math.h>
#include <stdint.h>

// B=2, T=2048, E=1024, H=16, HS=64. bf16 MFMA everywhere matmul-shaped.
// Workspace (u16 elems unless noted):
//   Wqkv_t [3072][1024], Wp_t [1024][1024], W1_t [4096][1024], W2_t [1024][4096]
//   h [4096][1024] (LN out, reused for LN2), QKV [4096][3072], Obuf [4096][1024]
//   f [4096][4096] overlaps QKV+Obuf exactly; x1 fp32 [4096][1024] after Obuf.
// Total ~84 MB.

typedef unsigned short u16;
typedef __attribute__((ext_vector_type(8))) short bf16x8;
typedef __attribute__((ext_vector_type(4))) float f32x4;

__device__ __forceinline__ u16 f2bf(float f) {
  unsigned int u = __float_as_uint(f);
  u += 0x7FFFu + ((u >> 16) & 1u);
  return (u16)(u >> 16);
}

__device__ __forceinline__ void async16(const u16* g, u16* l) {
  __builtin_amdgcn_global_load_lds(
      (const __attribute__((address_space(1))) unsigned int*)g,
      (__attribute__((address_space(3))) unsigned int*)l, 16, 0, 0);
}

// ---------- tiled transpose fp32 [batch][R][C] -> bf16 [batch][C][R] ----------
__global__ __launch_bounds__(256) void transpose_bf16(
    const float* __restrict__ src, u16* __restrict__ dst,
    int R, int C, long sbs, long dbs, int drs) {
  __shared__ float tile[32][33];
  int c0 = blockIdx.x * 32, r0 = blockIdx.y * 32;
  long sb = (long)blockIdx.z * sbs, db = (long)blockIdx.z * dbs;
  int tx = threadIdx.x & 31, ty = threadIdx.x >> 5;
  #pragma unroll
  for (int k = 0; k < 4; ++k)
    tile[ty + k * 8][tx] = src[sb + (long)(r0 + ty + k * 8) * C + c0 + tx];
  __syncthreads();
  #pragma unroll
  for (int k = 0; k < 4; ++k)
    dst[db + (long)(c0 + ty + k * 8) * drs + r0 + tx] = f2bf(tile[tx][ty + k * 8]);
}

// ---------- LayerNorm rows of 1024, bf16 out ----------
__global__ __launch_bounds__(256) void ln_bf16(
    const float* __restrict__ x, const float* __restrict__ g,
    const float* __restrict__ b, u16* __restrict__ out) {
  int row = blockIdx.x;
  const float* xr = x + (size_t)row * 1024;
  int t = threadIdx.x;
  float4 v = *(const float4*)(xr + t * 4);
  float s = v.x + v.y + v.z + v.w;
  float q = v.x * v.x + v.y * v.y + v.z * v.z + v.w * v.w;
  #pragma unroll
  for (int off = 32; off >= 1; off >>= 1) {
    s += __shfl_xor(s, off);
    q += __shfl_xor(q, off);
  }
  __shared__ float ss[4], qq[4];
  int wid = t >> 6;
  if ((t & 63) == 0) { ss[wid] = s; qq[wid] = q; }
  __syncthreads();
  float st = ss[0] + ss[1] + ss[2] + ss[3];
  float qt = qq[0] + qq[1] + qq[2] + qq[3];
  float mean = st * (1.0f / 1024.0f);
  float var = qt * (1.0f / 1024.0f) - mean * mean;
  float rstd = rsqrtf(var + 1e-5f);
  float4 gv = *(const float4*)(g + t * 4);
  float4 bv = *(const float4*)(b + t * 4);
  u16 o0 = f2bf((v.x - mean) * rstd * gv.x + bv.x);
  u16 o1 = f2bf((v.y - mean) * rstd * gv.y + bv.y);
  u16 o2 = f2bf((v.z - mean) * rstd * gv.z + bv.z);
  u16 o3 = f2bf((v.w - mean) * rstd * gv.w + bv.w);
  uint2 st2;
  st2.x = (unsigned)o0 | ((unsigned)o1 << 16);
  st2.y = (unsigned)o2 | ((unsigned)o3 << 16);
  *(uint2*)(out + (size_t)row * 1024 + t * 4) = st2;
}

// ---------- bf16 MFMA GEMM: C = A[M,K] @ Bt[N,K]^T (+bias +res, relu) ----------
// BN=128 fixed, BK=32, 256 threads (4 waves, 2x2), wave tile (BM/2)x64.
template <int BM>
__global__ __launch_bounds__(256) void gemm_bf16(
    const u16* __restrict__ A, const u16* __restrict__ Bt,
    const float* __restrict__ bias, const float* __restrict__ res,
    float* __restrict__ Cf, u16* __restrict__ Cb,
    int M, int N, int K, int relu) {
  constexpr int MI = BM / 32;
  constexpr int ACH = BM / 64;  // A staging chunks per wave
  __shared__ u16 As[BM * 32];
  __shared__ u16 Bs[128 * 32];
  int tid = threadIdx.x, wave = tid >> 6, lane = tid & 63;
  int wm = wave >> 1, wn = wave & 1;
  int lr = lane & 15, lq = lane >> 4;
  int bn = blockIdx.x * 128, bm = blockIdx.y * BM;
  f32x4 acc[MI][4];
  #pragma unroll
  for (int i = 0; i < MI; ++i)
    #pragma unroll
    for (int j = 0; j < 4; ++j) acc[i][j] = f32x4{0.f, 0.f, 0.f, 0.f};

  const u16* ag[ACH];
  #pragma unroll
  for (int j = 0; j < ACH; ++j) {
    int ca = wave * ACH + j;
    ag[j] = A + (size_t)(bm + ca * 16 + (lane >> 2)) * K + (lane & 3) * 8;
  }
  const u16* bg[2];
  #pragma unroll
  for (int j = 0; j < 2; ++j) {
    int cb = wave * 2 + j;
    bg[j] = Bt + (size_t)(bn + cb * 16 + (lane >> 2)) * K + (lane & 3) * 8;
  }

  for (int k0 = 0; k0 < K; k0 += 32) {
    #pragma unroll
    for (int j = 0; j < ACH; ++j)
      async16(ag[j] + k0, As + (wave * ACH + j) * 512);
    #pragma unroll
    for (int j = 0; j < 2; ++j)
      async16(bg[j] + k0, Bs + (wave * 2 + j) * 512);
    __syncthreads();
    bf16x8 af[MI], bf[4];
    #pragma unroll
    for (int mi = 0; mi < MI; ++mi)
      af[mi] = *(const bf16x8*)(As + (wm * (BM / 2) + mi * 16 + lr) * 32 + lq * 8);
    #pragma unroll
    for (int ni = 0; ni < 4; ++ni)
      bf[ni] = *(const bf16x8*)(Bs + (wn * 64 + ni * 16 + lr) * 32 + lq * 8);
    #pragma unroll
    for (int mi = 0; mi < MI; ++mi)
      #pragma unroll
      for (int ni = 0; ni < 4; ++ni)
        acc[mi][ni] = __builtin_amdgcn_mfma_f32_16x16x32_bf16(af[mi], bf[ni], acc[mi][ni], 0, 0, 0);
    __syncthreads();
  }

  #pragma unroll
  for (int mi = 0; mi < MI; ++mi) {
    #pragma unroll
    for (int r = 0; r < 4; ++r) {
      int row = bm + wm * (BM / 2) + mi * 16 + lq * 4 + r;
      #pragma unroll
      for (int ni = 0; ni < 4; ++ni) {
        int col = bn + wn * 64 + ni * 16 + lr;
        float v = acc[mi][ni][r];
        if (bias) v += bias[col];
        if (res) v += res[(size_t)row * N + col];
        if (relu) v = fmaxf(v, 0.f);
        if (Cb) Cb[(size_t)row * N + col] = f2bf(v);
        else Cf[(size_t)row * N + col] = v;
      }
    }
  }
}

// ---------- MFMA flash attention, bf16, BQ=64, BK=64 ----------
// QKV bf16 [4096][3072] rows (b*T+t), cols [Q | K | V] each h*64+d.
__global__ __launch_bounds__(256) void attn_mfma(
    const u16* __restrict__ QKV, u16* __restrict__ O) {
  __shared__ u16 Klds[2 * 64 * 32];  // [kstep][krow][32]
  __shared__ u16 Vt[64][68];         // V^T, padded
  __shared__ u16 Pl[4][16][72];      // per-wave P
  const int T = 2048;
  int qt = 31 - blockIdx.x;  // long blocks first
  int b = blockIdx.y >> 4, hh = blockIdx.y & 15;
  int tid = threadIdx.x, wave = tid >> 6, lane = tid & 63;
  int lr = lane & 15, lq = lane >> 4;
  const float c = 0.18033688f;  // 0.125 * log2(e)

  // loop-invariant Q A-fragments straight from global
  int qrow = qt * 64 + wave * 16 + lr;
  const u16* qp = QKV + (size_t)(b * T + qrow) * 3072 + hh * 64 + lq * 8;
  bf16x8 qf0 = *(const bf16x8*)qp;
  bf16x8 qf1 = *(const bf16x8*)(qp + 32);

  f32x4 of[4];
  #pragma unroll
  for (int i = 0; i < 4; ++i) of[i] = f32x4{0.f, 0.f, 0.f, 0.f};
  float m_i[4], l_i[4];
  #pragma unroll
  for (int i = 0; i < 4; ++i) { m_i[i] = -1e30f; l_i[i] = 0.f; }

  for (int kt = 0; kt <= qt; ++kt) {
    // K tile -> LDS [2][64][32] via async, 64B rows
    const u16* Kbase = QKV + (size_t)(b * T + kt * 64) * 3072 + 1024 + hh * 64;
    #pragma unroll
    for (int j = 0; j < 2; ++j) {
      int chunk = wave * 2 + j;
      int half = chunk >> 2, r0 = (chunk & 3) * 16;
      const u16* g = Kbase + (size_t)(r0 + (lane >> 2)) * 3072 + half * 32 + (lane & 3) * 8;
      async16(g, Klds + chunk * 512);
    }
    // V tile transposed -> Vt
    const u16* Vbase = QKV + (size_t)(b * T + kt * 64) * 3072 + 2048 + hh * 64;
    #pragma unroll
    for (int j = 0; j < 2; ++j) {
      int cch = tid + j * 256;
      int s = cch >> 3, d0 = (cch & 7) * 8;
      bf16x8 v8 = *(const bf16x8*)(Vbase + (size_t)s * 3072 + d0);
      #pragma unroll
      for (int e = 0; e < 8; ++e) Vt[d0 + e][s] = (u16)v8[e];
    }
    __syncthreads();

    // S = Q @ K^T
    f32x4 sf[4];
    #pragma unroll
    for (int i = 0; i < 4; ++i) sf[i] = f32x4{0.f, 0.f, 0.f, 0.f};
    #pragma unroll
    for (int ni = 0; ni < 4; ++ni) {
      bf16x8 b0 = *(const bf16x8*)(Klds + (ni * 16 + lr) * 32 + lq * 8);
      bf16x8 b1 = *(const bf16x8*)(Klds + 2048 + (ni * 16 + lr) * 32 + lq * 8);
      sf[ni] = __builtin_amdgcn_mfma_f32_16x16x32_bf16(qf0, b0, sf[ni], 0, 0, 0);
      sf[ni] = __builtin_amdgcn_mfma_f32_16x16x32_bf16(qf1, b1, sf[ni], 0, 0, 0);
    }
    if (kt == qt) {  // causal mask on diagonal tile
      #pragma unroll
      for (int ni = 0; ni < 4; ++ni) {
        int col = ni * 16 + lr;
        #pragma unroll
        for (int r = 0; r < 4; ++r) {
          int row = wave * 16 + lq * 4 + r;
          if (col > row) sf[ni][r] = -1e30f;
        }
      }
    }
    // online softmax (rows lq*4+r, replicated over the 16 lr lanes)
    float alpha[4];
    #pragma unroll
    for (int r = 0; r < 4; ++r) {
      float mx = fmaxf(fmaxf(sf[0][r], sf[1][r]), fmaxf(sf[2][r], sf[3][r]));
      mx = fmaxf(mx, __shfl_xor(mx, 1));
      mx = fmaxf(mx, __shfl_xor(mx, 2));
      mx = fmaxf(mx, __shfl_xor(mx, 4));
      mx = fmaxf(mx, __shfl_xor(mx, 8));
      float mnew = fmaxf(m_i[r], mx);
      alpha[r] = exp2f(c * (m_i[r] - mnew));
      float rs = 0.f;
      #pragma unroll
      for (int ni = 0; ni < 4; ++ni) {
        float p = exp2f(c * (sf[ni][r] - mnew));
        sf[ni][r] = p;
        rs += p;
      }
      rs += __shfl_xor(rs, 1);
      rs += __shfl_xor(rs, 2);
      rs += __shfl_xor(rs, 4);
      rs += __shfl_xor(rs, 8);
      l_i[r] = alpha[r] * l_i[r] + rs;
      m_i[r] = mnew;
    }
    // P -> wave-private LDS (C-layout -> A-layout round trip)
    #pragma unroll
    for (int ni = 0; ni < 4; ++ni)
      #pragma unroll
      for (int r = 0; r < 4; ++r)
        Pl[wave][lq * 4 + r][ni * 16 + lr] = f2bf(sf[ni][r]);
    #pragma unroll
    for (int ni = 0; ni < 4; ++ni)
      #pragma unroll
      for (int r = 0; r < 4; ++r)
        of[ni][r] *= alpha[r];
    // O += P @ V
    bf16x8 pa0 = *(const bf16x8*)&Pl[wave][lr][lq * 8];
    bf16x8 pa1 = *(const bf16x8*)&Pl[wave][lr][32 + lq * 8];
    #pragma unroll
    for (int ni = 0; ni < 4; ++ni) {
      bf16x8 v0 = *(const bf16x8*)&Vt[ni * 16 + lr][lq * 8];
      bf16x8 v1 = *(const bf16x8*)&Vt[ni * 16 + lr][32 + lq * 8];
      of[ni] = __builtin_amdgcn_mfma_f32_16x16x32_bf16(pa0, v0, of[ni], 0, 0, 0);
      of[ni] = __builtin_amdgcn_mfma_f32_16x16x32_bf16(pa1, v1, of[ni], 0, 0, 0);
    }
    __syncthreads();
  }
  #pragma unroll
  for (int r = 0; r < 4; ++r) {
    int row = qt * 64 + wave * 16 + lq * 4 + r;
    float inv = 1.0f / l_i[r];
    u16* op = O + (size_t)(b * T + row) * 1024 + hh * 64;
    #pragma unroll
    for (int ni = 0; ni < 4; ++ni)
      op[ni * 16 + lr] = f2bf(of[ni][r] * inv);
  }
}

extern "C" void kernel_launch(void* const* d_in, const int* in_sizes, int n_in,
                              void* d_out, int out_size, void* d_ws, size_t ws_size,
                              hipStream_t stream) {
  const float* x   = (const float*)d_in[0];
  const float* Wq  = (const float*)d_in[1];
  const float* Wk  = (const float*)d_in[2];
  const float* Wv  = (const float*)d_in[3];
  const float* Wp  = (const float*)d_in[4];
  const float* bp  = (const float*)d_in[5];
  const float* W1  = (const float*)d_in[6];
  const float* b1  = (const float*)d_in[7];
  const float* W2  = (const float*)d_in[8];
  const float* b2  = (const float*)d_in[9];
  const float* g1  = (const float*)d_in[10];
  const float* be1 = (const float*)d_in[11];
  const float* g2  = (const float*)d_in[12];
  const float* be2 = (const float*)d_in[13];
  float* out = (float*)d_out;

  u16* ws16   = (u16*)d_ws;
  u16* Wqkv_t = ws16;                    // 3,145,728
  u16* Wp_t   = Wqkv_t + 3145728;        // 1,048,576
  u16* W1_t   = Wp_t + 1048576;          // 4,194,304
  u16* W2_t   = W1_t + 4194304;          // 4,194,304
  u16* h      = W2_t + 4194304;          // 4,194,304 (LN1 out; reused for LN2)
  u16* QKV    = h + 4194304;             // 12,582,912
  u16* Obuf   = QKV + 12582912;          // 4,194,304
  u16* f      = QKV;                     // 16,777,216 (overlaps QKV+Obuf exactly)
  float* x1   = (float*)(Obuf + 4194304);// 4,194,304 floats

  // weight repacks -> bf16 [N][K]
  transpose_bf16<<<dim3(2, 32, 16), 256, 0, stream>>>(Wq, Wqkv_t, 1024, 64, 65536, 65536, 1024);
  transpose_bf16<<<dim3(2, 32, 16), 256, 0, stream>>>(Wk, Wqkv_t + 1048576, 1024, 64, 65536, 65536, 1024);
  transpose_bf16<<<dim3(2, 32, 16), 256, 0, stream>>>(Wv, Wqkv_t + 2097152, 1024, 64, 65536, 65536, 1024);
  transpose_bf16<<<dim3(32, 32, 1), 256, 0, stream>>>(Wp, Wp_t, 1024, 1024, 0, 0, 1024);
  transpose_bf16<<<dim3(128, 32, 1), 256, 0, stream>>>(W1, W1_t, 1024, 4096, 0, 0, 1024);
  transpose_bf16<<<dim3(32, 128, 1), 256, 0, stream>>>(W2, W2_t, 4096, 1024, 0, 0, 4096);

  ln_bf16<<<4096, 256, 0, stream>>>(x, g1, be1, h);
  gemm_bf16<128><<<dim3(24, 32), 256, 0, stream>>>(h, Wqkv_t, nullptr, nullptr,
                                                   nullptr, QKV, 4096, 3072, 1024, 0);
  attn_mfma<<<dim3(32, 32), 256, 0, stream>>>(QKV, Obuf);
  gemm_bf16<64><<<dim3(8, 64), 256, 0, stream>>>(Obuf, Wp_t, bp, x,
                                                 x1, nullptr, 4096, 1024, 1024, 0);
  ln_bf16<<<4096, 256, 0, stream>>>(x1, g2, be2, h);
  gemm_bf16<128><<<dim3(32, 32), 256, 0, stream>>>(h, W1_t, b1, nullptr,
                                                   nullptr, f, 4096, 4096, 1024, 1);
  gemm_bf16<64><<<dim3(8, 64), 256, 0, stream>>>(f, W2_t, b2, x1,
                                                 out, nullptr, 4096, 1024, 4096, 0);
}

// Round 3
// 442.732 us; speedup vs baseline: 4.9714x; 1.2356x over previous
//
#include <hip/hip_runtime.h>
#include <math.h>
#include <stdint.h>

// B=2, T=2048, E=1024, H=16, HS=64. bf16 MFMA, XOR-swizzled 128B-row LDS, BK=64.
typedef unsigned short u16;
typedef __attribute__((ext_vector_type(8))) short bf16x8;
typedef __attribute__((ext_vector_type(4))) float f32x4;

__device__ __forceinline__ u16 f2bf(float f) {
  unsigned int u = __float_as_uint(f);
  u += 0x7FFFu + ((u >> 16) & 1u);
  return (u16)(u >> 16);
}

__device__ __forceinline__ void async16(const u16* g, u16* l) {
  __builtin_amdgcn_global_load_lds(
      (const __attribute__((address_space(1))) unsigned int*)g,
      (__attribute__((address_space(3))) unsigned int*)l, 16, 0, 0);
}

// ---------- tiled transpose fp32 [batch][R][C] -> bf16 [batch][C][R], ×scale ----------
__global__ __launch_bounds__(256) void transpose_bf16(
    const float* __restrict__ src, u16* __restrict__ dst,
    int R, int C, long sbs, long dbs, int drs, float scale) {
  __shared__ float tile[32][33];
  int c0 = blockIdx.x * 32, r0 = blockIdx.y * 32;
  long sb = (long)blockIdx.z * sbs, db = (long)blockIdx.z * dbs;
  int tx = threadIdx.x & 31, ty = threadIdx.x >> 5;
  #pragma unroll
  for (int k = 0; k < 4; ++k)
    tile[ty + k * 8][tx] = src[sb + (long)(r0 + ty + k * 8) * C + c0 + tx];
  __syncthreads();
  #pragma unroll
  for (int k = 0; k < 4; ++k)
    dst[db + (long)(c0 + ty + k * 8) * drs + r0 + tx] =
        f2bf(tile[tx][ty + k * 8] * scale);
}

// ---------- V^T builder: QKV V-cols -> VT [h][d=64][4096] bf16 ----------
__global__ __launch_bounds__(256) void vtrans(
    const u16* __restrict__ QKV, u16* __restrict__ VT) {
  __shared__ u16 Tl[64][72];
  int bt = blockIdx.x, h = blockIdx.y;
  int t = threadIdx.x;
  int r = t >> 3, c0 = (t & 7) << 3;
  const u16* src = QKV + (size_t)(bt * 64 + r) * 3072 + 2048 + h * 64 + c0;
  #pragma unroll
  for (int half = 0; half < 2; ++half) {
    bf16x8 v = *(const bf16x8*)(src + (size_t)(half * 32) * 3072);
    #pragma unroll
    for (int e = 0; e < 8; ++e) Tl[r + half * 32][c0 + e] = (u16)v[e];
  }
  __syncthreads();
  #pragma unroll
  for (int half = 0; half < 2; ++half) {
    int d = (t >> 3) + half * 32, s0 = (t & 7) << 3;
    bf16x8 o;
    #pragma unroll
    for (int e = 0; e < 8; ++e) o[e] = (short)Tl[s0 + e][d];
    *(bf16x8*)(VT + (size_t)(h * 64 + d) * 4096 + bt * 64 + s0) = o;
  }
}

// ---------- LayerNorm rows of 1024, bf16 out ----------
__global__ __launch_bounds__(256) void ln_bf16(
    const float* __restrict__ x, const float* __restrict__ g,
    const float* __restrict__ b, u16* __restrict__ out) {
  int row = blockIdx.x;
  const float* xr = x + (size_t)row * 1024;
  int t = threadIdx.x;
  float4 v = *(const float4*)(xr + t * 4);
  float s = v.x + v.y + v.z + v.w;
  float q = v.x * v.x + v.y * v.y + v.z * v.z + v.w * v.w;
  #pragma unroll
  for (int off = 32; off >= 1; off >>= 1) {
    s += __shfl_xor(s, off);
    q += __shfl_xor(q, off);
  }
  __shared__ float ss[4], qq[4];
  int wid = t >> 6;
  if ((t & 63) == 0) { ss[wid] = s; qq[wid] = q; }
  __syncthreads();
  float st = ss[0] + ss[1] + ss[2] + ss[3];
  float qt = qq[0] + qq[1] + qq[2] + qq[3];
  float mean = st * (1.0f / 1024.0f);
  float var = qt * (1.0f / 1024.0f) - mean * mean;
  float rstd = rsqrtf(var + 1e-5f);
  float4 gv = *(const float4*)(g + t * 4);
  float4 bv = *(const float4*)(b + t * 4);
  u16 o0 = f2bf((v.x - mean) * rstd * gv.x + bv.x);
  u16 o1 = f2bf((v.y - mean) * rstd * gv.y + bv.y);
  u16 o2 = f2bf((v.z - mean) * rstd * gv.z + bv.z);
  u16 o3 = f2bf((v.w - mean) * rstd * gv.w + bv.w);
  uint2 st2;
  st2.x = (unsigned)o0 | ((unsigned)o1 << 16);
  st2.y = (unsigned)o2 | ((unsigned)o3 << 16);
  *(uint2*)(out + (size_t)row * 1024 + t * 4) = st2;
}

// ---------- bf16 MFMA GEMM: C = A[M,K] @ Bt[N,K]^T, BK=64, swizzled LDS ----------
template <int BM, int BN>
__global__ __launch_bounds__(256) void gemm_bf16(
    const u16* __restrict__ A, const u16* __restrict__ Bt,
    const float* __restrict__ bias, const float* __restrict__ res,
    float* __restrict__ Cf, u16* __restrict__ Cb,
    int M, int N, int K, int relu) {
  constexpr int MI = BM / 32, NI = BN / 32;
  constexpr int ACH = BM / 32, BCH = BN / 32;  // staging chunks per wave
  __shared__ u16 As[BM * 64];
  __shared__ u16 Bs[BN * 64];
  int tid = threadIdx.x, wave = tid >> 6, lane = tid & 63;
  int wm = wave >> 1, wn = wave & 1;
  int lr = lane & 15, lq = lane >> 4;
  int lrow = lane >> 3, kblk = (lane & 7) ^ (lrow & 7);
  int bn = blockIdx.x * BN, bm = blockIdx.y * BM;
  f32x4 acc[MI][NI];
  #pragma unroll
  for (int i = 0; i < MI; ++i)
    #pragma unroll
    for (int j = 0; j < NI; ++j) acc[i][j] = f32x4{0.f, 0.f, 0.f, 0.f};

  const u16* ag[ACH];
  #pragma unroll
  for (int j = 0; j < ACH; ++j) {
    int c = wave * ACH + j;
    ag[j] = A + (size_t)(bm + c * 8 + lrow) * K + kblk * 8;
  }
  const u16* bg[BCH];
  #pragma unroll
  for (int j = 0; j < BCH; ++j) {
    int c = wave * BCH + j;
    bg[j] = Bt + (size_t)(bn + c * 8 + lrow) * K + kblk * 8;
  }

  for (int k0 = 0; k0 < K; k0 += 64) {
    #pragma unroll
    for (int j = 0; j < ACH; ++j)
      async16(ag[j] + k0, As + (wave * ACH + j) * 512);
    #pragma unroll
    for (int j = 0; j < BCH; ++j)
      async16(bg[j] + k0, Bs + (wave * BCH + j) * 512);
    __syncthreads();
    #pragma unroll
    for (int kk = 0; kk < 2; ++kk) {
      bf16x8 af[MI], bfr[NI];
      #pragma unroll
      for (int mi = 0; mi < MI; ++mi) {
        int row = wm * (BM / 2) + mi * 16 + lr;
        af[mi] = *(const bf16x8*)(As + row * 64 + (((kk << 2) + lq) ^ (lr & 7)) * 8);
      }
      #pragma unroll
      for (int ni = 0; ni < NI; ++ni) {
        int row = wn * (BN / 2) + ni * 16 + lr;
        bfr[ni] = *(const bf16x8*)(Bs + row * 64 + (((kk << 2) + lq) ^ (lr & 7)) * 8);
      }
      #pragma unroll
      for (int mi = 0; mi < MI; ++mi)
        #pragma unroll
        for (int ni = 0; ni < NI; ++ni)
          acc[mi][ni] = __builtin_amdgcn_mfma_f32_16x16x32_bf16(af[mi], bfr[ni], acc[mi][ni], 0, 0, 0);
    }
    __syncthreads();
  }

  #pragma unroll
  for (int mi = 0; mi < MI; ++mi) {
    #pragma unroll
    for (int r = 0; r < 4; ++r) {
      int row = bm + wm * (BM / 2) + mi * 16 + lq * 4 + r;
      #pragma unroll
      for (int ni = 0; ni < NI; ++ni) {
        int col = bn + wn * (BN / 2) + ni * 16 + lr;
        float v = acc[mi][ni][r];
        if (bias) v += bias[col];
        if (res) v += res[(size_t)row * N + col];
        if (relu) v = fmaxf(v, 0.f);
        if (Cb) Cb[(size_t)row * N + col] = f2bf(v);
        else Cf[(size_t)row * N + col] = v;
      }
    }
  }
}

// ---------- MFMA flash attention: fixed-max softmax, deferred normalization ----------
// QKV bf16 [4096][3072] (Q pre-scaled by 0.125*log2e); VT bf16 [16][64][4096].
__global__ __launch_bounds__(256) void attn_mfma(
    const u16* __restrict__ QKV, const u16* __restrict__ VT,
    u16* __restrict__ O) {
  __shared__ u16 Klds[64 * 64];
  __shared__ u16 Vl[64 * 64];
  __shared__ u16 Pl[4][16][72];
  int qt = 31 - blockIdx.x;  // long blocks first
  int b = blockIdx.y >> 4, hh = blockIdx.y & 15;
  int tid = threadIdx.x, wave = tid >> 6, lane = tid & 63;
  int lr = lane & 15, lq = lane >> 4;
  int lrow = lane >> 3, kb = (lane & 7) ^ (lrow & 7);

  int qrow = qt * 64 + wave * 16 + lr;
  const u16* qp = QKV + (size_t)(b * 2048 + qrow) * 3072 + hh * 64 + lq * 8;
  bf16x8 qf0 = *(const bf16x8*)qp;
  bf16x8 qf1 = *(const bf16x8*)(qp + 32);

  f32x4 of[4];
  float lsum[4];
  #pragma unroll
  for (int i = 0; i < 4; ++i) { of[i] = f32x4{0.f, 0.f, 0.f, 0.f}; lsum[i] = 0.f; }

  const u16* kg[2];
  const u16* vg[2];
  #pragma unroll
  for (int j = 0; j < 2; ++j) {
    int c = wave * 2 + j;
    kg[j] = QKV + (size_t)(b * 2048 + c * 8 + lrow) * 3072 + 1024 + hh * 64 + kb * 8;
    vg[j] = VT + (size_t)(hh * 64 + c * 8 + lrow) * 4096 + b * 2048 + kb * 8;
  }

  for (int kt = 0; kt <= qt; ++kt) {
    #pragma unroll
    for (int j = 0; j < 2; ++j)
      async16(kg[j] + (size_t)kt * 64 * 3072, Klds + (wave * 2 + j) * 512);
    #pragma unroll
    for (int j = 0; j < 2; ++j)
      async16(vg[j] + kt * 64, Vl + (wave * 2 + j) * 512);
    __syncthreads();

    // S = Qs @ K^T (pre-scaled)
    f32x4 sf[4];
    #pragma unroll
    for (int i = 0; i < 4; ++i) sf[i] = f32x4{0.f, 0.f, 0.f, 0.f};
    #pragma unroll
    for (int ni = 0; ni < 4; ++ni) {
      int row = ni * 16 + lr;
      bf16x8 k0 = *(const bf16x8*)(Klds + row * 64 + ((lq) ^ (lr & 7)) * 8);
      bf16x8 k1 = *(const bf16x8*)(Klds + row * 64 + ((4 + lq) ^ (lr & 7)) * 8);
      sf[ni] = __builtin_amdgcn_mfma_f32_16x16x32_bf16(qf0, k0, sf[ni], 0, 0, 0);
      sf[ni] = __builtin_amdgcn_mfma_f32_16x16x32_bf16(qf1, k1, sf[ni], 0, 0, 0);
    }
    if (kt == qt) {
      #pragma unroll
      for (int ni = 0; ni < 4; ++ni) {
        int col = ni * 16 + lr;
        #pragma unroll
        for (int r = 0; r < 4; ++r) {
          int row = wave * 16 + lq * 4 + r;
          if (col > row) sf[ni][r] = -1e30f;
        }
      }
    }
    // p = exp2(s); accumulate l per-lane; P -> wave-private LDS (A-layout round trip)
    #pragma unroll
    for (int ni = 0; ni < 4; ++ni)
      #pragma unroll
      for (int r = 0; r < 4; ++r) {
        float p = exp2f(sf[ni][r]);
        sf[ni][r] = p;
        lsum[r] += p;
        Pl[wave][lq * 4 + r][ni * 16 + lr] = f2bf(p);
      }
    bf16x8 pa0 = *(const bf16x8*)(&Pl[wave][lr][lq * 8]);
    bf16x8 pa1 = *(const bf16x8*)(&Pl[wave][lr][32 + lq * 8]);
    #pragma unroll
    for (int ni = 0; ni < 4; ++ni) {
      int row = ni * 16 + lr;
      bf16x8 v0 = *(const bf16x8*)(Vl + row * 64 + ((lq) ^ (lr & 7)) * 8);
      bf16x8 v1 = *(const bf16x8*)(Vl + row * 64 + ((4 + lq) ^ (lr & 7)) * 8);
      of[ni] = __builtin_amdgcn_mfma_f32_16x16x32_bf16(pa0, v0, of[ni], 0, 0, 0);
      of[ni] = __builtin_amdgcn_mfma_f32_16x16x32_bf16(pa1, v1, of[ni], 0, 0, 0);
    }
    __syncthreads();
  }
  #pragma unroll
  for (int r = 0; r < 4; ++r) {
    float l = lsum[r];
    l += __shfl_xor(l, 1);
    l += __shfl_xor(l, 2);
    l += __shfl_xor(l, 4);
    l += __shfl_xor(l, 8);
    float inv = 1.0f / l;
    int row = qt * 64 + wave * 16 + lq * 4 + r;
    u16* op = O + (size_t)(b * 2048 + row) * 1024 + hh * 64;
    #pragma unroll
    for (int ni = 0; ni < 4; ++ni)
      op[ni * 16 + lr] = f2bf(of[ni][r] * inv);
  }
}

extern "C" void kernel_launch(void* const* d_in, const int* in_sizes, int n_in,
                              void* d_out, int out_size, void* d_ws, size_t ws_size,
                              hipStream_t stream) {
  const float* x   = (const float*)d_in[0];
  const float* Wq  = (const float*)d_in[1];
  const float* Wk  = (const float*)d_in[2];
  const float* Wv  = (const float*)d_in[3];
  const float* Wp  = (const float*)d_in[4];
  const float* bp  = (const float*)d_in[5];
  const float* W1  = (const float*)d_in[6];
  const float* b1  = (const float*)d_in[7];
  const float* W2  = (const float*)d_in[8];
  const float* b2  = (const float*)d_in[9];
  const float* g1  = (const float*)d_in[10];
  const float* be1 = (const float*)d_in[11];
  const float* g2  = (const float*)d_in[12];
  const float* be2 = (const float*)d_in[13];
  float* out = (float*)d_out;

  u16* ws16   = (u16*)d_ws;
  u16* Wqkv_t = ws16;                      // 3,145,728
  u16* Wp_t   = Wqkv_t + 3145728;          // 1,048,576
  u16* W1_t   = Wp_t + 1048576;            // 4,194,304
  u16* W2_t   = W1_t + 4194304;            // 4,194,304
  u16* h      = W2_t + 4194304;            // 4,194,304 (LN1 out; reused for LN2)
  u16* QKV    = h + 4194304;               // 12,582,912
  u16* Obuf   = QKV + 12582912;            // 4,194,304
  u16* f      = QKV;                       // 16,777,216 (overlaps QKV+Obuf)
  float* x1   = (float*)(Obuf + 4194304);  // 4,194,304 floats
  u16* VT     = (u16*)(x1 + 4194304);      // 4,194,304

  const float qsc = 0.18033688f;  // 0.125 * log2(e), folded into Wq
  transpose_bf16<<<dim3(2, 32, 16), 256, 0, stream>>>(Wq, Wqkv_t, 1024, 64, 65536, 65536, 1024, qsc);
  transpose_bf16<<<dim3(2, 32, 16), 256, 0, stream>>>(Wk, Wqkv_t + 1048576, 1024, 64, 65536, 65536, 1024, 1.f);
  transpose_bf16<<<dim3(2, 32, 16), 256, 0, stream>>>(Wv, Wqkv_t + 2097152, 1024, 64, 65536, 65536, 1024, 1.f);
  transpose_bf16<<<dim3(32, 32, 1), 256, 0, stream>>>(Wp, Wp_t, 1024, 1024, 0, 0, 1024, 1.f);
  transpose_bf16<<<dim3(128, 32, 1), 256, 0, stream>>>(W1, W1_t, 1024, 4096, 0, 0, 1024, 1.f);
  transpose_bf16<<<dim3(32, 128, 1), 256, 0, stream>>>(W2, W2_t, 4096, 1024, 0, 0, 4096, 1.f);

  ln_bf16<<<4096, 256, 0, stream>>>(x, g1, be1, h);
  gemm_bf16<128, 128><<<dim3(24, 32), 256, 0, stream>>>(h, Wqkv_t, nullptr, nullptr,
                                                        nullptr, QKV, 4096, 3072, 1024, 0);
  vtrans<<<dim3(64, 16), 256, 0, stream>>>(QKV, VT);
  attn_mfma<<<dim3(32, 32), 256, 0, stream>>>(QKV, VT, Obuf);
  gemm_bf16<128, 64><<<dim3(16, 32), 256, 0, stream>>>(Obuf, Wp_t, bp, x,
                                                       x1, nullptr, 4096, 1024, 1024, 0);
  ln_bf16<<<4096, 256, 0, stream>>>(x1, g2, be2, h);
  gemm_bf16<128, 128><<<dim3(32, 32), 256, 0, stream>>>(h, W1_t, b1, nullptr,
                                                        nullptr, f, 4096, 4096, 1024, 1);
  gemm_bf16<128, 64><<<dim3(16, 32), 256, 0, stream>>>(f, W2_t, b2, x1,
                                                       out, nullptr, 4096, 1024, 4096, 0);
}

// Round 4
// 415.127 us; speedup vs baseline: 5.3019x; 1.0665x over previous
//
#include <hip/hip_runtime.h>
#include <math.h>
#include <stdint.h>

// B=2, T=2048, E=1024, H=16, HS=64. bf16 MFMA.
// Pipelined GEMM: global->reg prefetch, double-buffered LDS, 1 barrier/K-iter.
typedef unsigned short u16;
typedef __attribute__((ext_vector_type(8))) short bf16x8;
typedef __attribute__((ext_vector_type(4))) float f32x4;

__device__ __forceinline__ u16 f2bf(float f) {
  unsigned int u = __float_as_uint(f);
  u += 0x7FFFu + ((u >> 16) & 1u);
  return (u16)(u >> 16);
}

// ---------- tiled transpose fp32 [batch][R][C] -> bf16 [batch][C][R], ×scale ----------
__global__ __launch_bounds__(256) void transpose_bf16(
    const float* __restrict__ src, u16* __restrict__ dst,
    int R, int C, long sbs, long dbs, int drs, float scale) {
  __shared__ float tile[32][33];
  int c0 = blockIdx.x * 32, r0 = blockIdx.y * 32;
  long sb = (long)blockIdx.z * sbs, db = (long)blockIdx.z * dbs;
  int tx = threadIdx.x & 31, ty = threadIdx.x >> 5;
  #pragma unroll
  for (int k = 0; k < 4; ++k)
    tile[ty + k * 8][tx] = src[sb + (long)(r0 + ty + k * 8) * C + c0 + tx];
  __syncthreads();
  #pragma unroll
  for (int k = 0; k < 4; ++k)
    dst[db + (long)(c0 + ty + k * 8) * drs + r0 + tx] =
        f2bf(tile[tx][ty + k * 8] * scale);
}

// ---------- V^T builder: QKV V-cols -> VT [h][d=64][4096] bf16 ----------
__global__ __launch_bounds__(256) void vtrans(
    const u16* __restrict__ QKV, u16* __restrict__ VT) {
  __shared__ u16 Tl[64][72];
  int bt = blockIdx.x, h = blockIdx.y;
  int t = threadIdx.x;
  int r = t >> 3, c0 = (t & 7) << 3;
  const u16* src = QKV + (size_t)(bt * 64 + r) * 3072 + 2048 + h * 64 + c0;
  #pragma unroll
  for (int half = 0; half < 2; ++half) {
    bf16x8 v = *(const bf16x8*)(src + (size_t)(half * 32) * 3072);
    #pragma unroll
    for (int e = 0; e < 8; ++e) Tl[r + half * 32][c0 + e] = (u16)v[e];
  }
  __syncthreads();
  #pragma unroll
  for (int half = 0; half < 2; ++half) {
    int d = (t >> 3) + half * 32, s0 = (t & 7) << 3;
    bf16x8 o;
    #pragma unroll
    for (int e = 0; e < 8; ++e) o[e] = (short)Tl[s0 + e][d];
    *(bf16x8*)(VT + (size_t)(h * 64 + d) * 4096 + bt * 64 + s0) = o;
  }
}

// ---------- LayerNorm rows of 1024, bf16 out ----------
__global__ __launch_bounds__(256) void ln_bf16(
    const float* __restrict__ x, const float* __restrict__ g,
    const float* __restrict__ b, u16* __restrict__ out) {
  int row = blockIdx.x;
  const float* xr = x + (size_t)row * 1024;
  int t = threadIdx.x;
  float4 v = *(const float4*)(xr + t * 4);
  float s = v.x + v.y + v.z + v.w;
  float q = v.x * v.x + v.y * v.y + v.z * v.z + v.w * v.w;
  #pragma unroll
  for (int off = 32; off >= 1; off >>= 1) {
    s += __shfl_xor(s, off);
    q += __shfl_xor(q, off);
  }
  __shared__ float ss[4], qq[4];
  int wid = t >> 6;
  if ((t & 63) == 0) { ss[wid] = s; qq[wid] = q; }
  __syncthreads();
  float st = ss[0] + ss[1] + ss[2] + ss[3];
  float qt = qq[0] + qq[1] + qq[2] + qq[3];
  float mean = st * (1.0f / 1024.0f);
  float var = qt * (1.0f / 1024.0f) - mean * mean;
  float rstd = rsqrtf(var + 1e-5f);
  float4 gv = *(const float4*)(g + t * 4);
  float4 bv = *(const float4*)(b + t * 4);
  u16 o0 = f2bf((v.x - mean) * rstd * gv.x + bv.x);
  u16 o1 = f2bf((v.y - mean) * rstd * gv.y + bv.y);
  u16 o2 = f2bf((v.z - mean) * rstd * gv.z + bv.z);
  u16 o3 = f2bf((v.w - mean) * rstd * gv.w + bv.w);
  uint2 st2;
  st2.x = (unsigned)o0 | ((unsigned)o1 << 16);
  st2.y = (unsigned)o2 | ((unsigned)o3 << 16);
  *(uint2*)(out + (size_t)row * 1024 + t * 4) = st2;
}

// ---------- pipelined bf16 MFMA GEMM: C = A[M,K] @ Bt[N,K]^T ----------
// BK=64, 256 threads (4 waves 2x2), double-buffered LDS, reg prefetch.
template <int BM, int BN>
__global__ __launch_bounds__(256) void gemm_bf16(
    const u16* __restrict__ A, const u16* __restrict__ Bt,
    const float* __restrict__ bias, const float* __restrict__ res,
    float* __restrict__ Cf, u16* __restrict__ Cb,
    int M, int N, int K, int relu) {
  constexpr int MI = BM / 32, NI = BN / 32;
  constexpr int ACH = BM / 32, BCH = BN / 32;  // 1KB chunks per wave
  __shared__ u16 As[2][BM * 64];
  __shared__ u16 Bs[2][BN * 64];
  int tid = threadIdx.x, wave = tid >> 6, lane = tid & 63;
  int wm = wave >> 1, wn = wave & 1;
  int lr = lane & 15, lq = lane >> 4;
  int lrow = lane >> 3, kblk = (lane & 7) ^ (lrow & 7);
  int bn = blockIdx.x * BN, bm = blockIdx.y * BM;
  f32x4 acc[MI][NI];
  #pragma unroll
  for (int i = 0; i < MI; ++i)
    #pragma unroll
    for (int j = 0; j < NI; ++j) acc[i][j] = f32x4{0.f, 0.f, 0.f, 0.f};

  const u16* ag[ACH];
  #pragma unroll
  for (int j = 0; j < ACH; ++j) {
    int c = wave * ACH + j;
    ag[j] = A + (size_t)(bm + c * 8 + lrow) * K + kblk * 8;
  }
  const u16* bg[BCH];
  #pragma unroll
  for (int j = 0; j < BCH; ++j) {
    int c = wave * BCH + j;
    bg[j] = Bt + (size_t)(bn + c * 8 + lrow) * K + kblk * 8;
  }

  bf16x8 ra[ACH], rb[BCH];
  #pragma unroll
  for (int j = 0; j < ACH; ++j) ra[j] = *(const bf16x8*)(ag[j]);
  #pragma unroll
  for (int j = 0; j < BCH; ++j) rb[j] = *(const bf16x8*)(bg[j]);

  int nIter = K >> 6;
  for (int it = 0; it < nIter; ++it) {
    int buf = it & 1;
    #pragma unroll
    for (int j = 0; j < ACH; ++j)
      *(bf16x8*)(&As[buf][(wave * ACH + j) * 512 + lane * 8]) = ra[j];
    #pragma unroll
    for (int j = 0; j < BCH; ++j)
      *(bf16x8*)(&Bs[buf][(wave * BCH + j) * 512 + lane * 8]) = rb[j];
    __syncthreads();
    if (it + 1 < nIter) {
      int k0 = (it + 1) << 6;
      #pragma unroll
      for (int j = 0; j < ACH; ++j) ra[j] = *(const bf16x8*)(ag[j] + k0);
      #pragma unroll
      for (int j = 0; j < BCH; ++j) rb[j] = *(const bf16x8*)(bg[j] + k0);
    }
    #pragma unroll
    for (int kk = 0; kk < 2; ++kk) {
      bf16x8 af[MI], bfr[NI];
      #pragma unroll
      for (int mi = 0; mi < MI; ++mi) {
        int row = wm * (BM / 2) + mi * 16 + lr;
        af[mi] = *(const bf16x8*)(&As[buf][row * 64 + (((kk << 2) + lq) ^ (lr & 7)) * 8]);
      }
      #pragma unroll
      for (int ni = 0; ni < NI; ++ni) {
        int row = wn * (BN / 2) + ni * 16 + lr;
        bfr[ni] = *(const bf16x8*)(&Bs[buf][row * 64 + (((kk << 2) + lq) ^ (lr & 7)) * 8]);
      }
      #pragma unroll
      for (int mi = 0; mi < MI; ++mi)
        #pragma unroll
        for (int ni = 0; ni < NI; ++ni)
          acc[mi][ni] = __builtin_amdgcn_mfma_f32_16x16x32_bf16(af[mi], bfr[ni], acc[mi][ni], 0, 0, 0);
    }
    // no trailing barrier: next iter writes the other buffer; its pre-compute
    // barrier orders those writes after every wave's reads of that buffer.
  }

  #pragma unroll
  for (int mi = 0; mi < MI; ++mi) {
    #pragma unroll
    for (int r = 0; r < 4; ++r) {
      int row = bm + wm * (BM / 2) + mi * 16 + lq * 4 + r;
      #pragma unroll
      for (int ni = 0; ni < NI; ++ni) {
        int col = bn + wn * (BN / 2) + ni * 16 + lr;
        float v = acc[mi][ni][r];
        if (bias) v += bias[col];
        if (res) v += res[(size_t)row * N + col];
        if (relu) v = fmaxf(v, 0.f);
        if (Cb) Cb[(size_t)row * N + col] = f2bf(v);
        else Cf[(size_t)row * N + col] = v;
      }
    }
  }
}

// ---------- pipelined MFMA flash attention: fixed-max softmax, dbuf K/V ----------
// QKV bf16 [4096][3072] (Q pre-scaled by 0.125*log2e); VT bf16 [16][64][4096].
__global__ __launch_bounds__(256) void attn_mfma(
    const u16* __restrict__ QKV, const u16* __restrict__ VT,
    u16* __restrict__ O) {
  __shared__ u16 Klds[2][64 * 64];
  __shared__ u16 Vl[2][64 * 64];
  __shared__ u16 Pl[4][16][72];
  int qt = 31 - blockIdx.x;  // long blocks first
  int b = blockIdx.y >> 4, hh = blockIdx.y & 15;
  int tid = threadIdx.x, wave = tid >> 6, lane = tid & 63;
  int lr = lane & 15, lq = lane >> 4;
  int lrow = lane >> 3, kb = (lane & 7) ^ (lrow & 7);

  int qrow = qt * 64 + wave * 16 + lr;
  const u16* qp = QKV + (size_t)(b * 2048 + qrow) * 3072 + hh * 64 + lq * 8;
  bf16x8 qf0 = *(const bf16x8*)qp;
  bf16x8 qf1 = *(const bf16x8*)(qp + 32);

  f32x4 of[4];
  float lsum[4];
  #pragma unroll
  for (int i = 0; i < 4; ++i) { of[i] = f32x4{0.f, 0.f, 0.f, 0.f}; lsum[i] = 0.f; }

  const u16* kg[2];
  const u16* vg[2];
  #pragma unroll
  for (int j = 0; j < 2; ++j) {
    int c = wave * 2 + j;
    kg[j] = QKV + (size_t)(b * 2048 + c * 8 + lrow) * 3072 + 1024 + hh * 64 + kb * 8;
    vg[j] = VT + (size_t)(hh * 64 + c * 8 + lrow) * 4096 + b * 2048 + kb * 8;
  }

  bf16x8 rk[2], rv[2];
  #pragma unroll
  for (int j = 0; j < 2; ++j) {
    rk[j] = *(const bf16x8*)(kg[j]);
    rv[j] = *(const bf16x8*)(vg[j]);
  }

  for (int kt = 0; kt <= qt; ++kt) {
    int buf = kt & 1;
    #pragma unroll
    for (int j = 0; j < 2; ++j) {
      *(bf16x8*)(&Klds[buf][(wave * 2 + j) * 512 + lane * 8]) = rk[j];
      *(bf16x8*)(&Vl[buf][(wave * 2 + j) * 512 + lane * 8]) = rv[j];
    }
    __syncthreads();
    if (kt < qt) {
      #pragma unroll
      for (int j = 0; j < 2; ++j) {
        rk[j] = *(const bf16x8*)(kg[j] + (size_t)(kt + 1) * 64 * 3072);
        rv[j] = *(const bf16x8*)(vg[j] + (kt + 1) * 64);
      }
    }

    // S = Qs @ K^T (pre-scaled)
    f32x4 sf[4];
    #pragma unroll
    for (int i = 0; i < 4; ++i) sf[i] = f32x4{0.f, 0.f, 0.f, 0.f};
    #pragma unroll
    for (int ni = 0; ni < 4; ++ni) {
      int row = ni * 16 + lr;
      bf16x8 k0 = *(const bf16x8*)(&Klds[buf][row * 64 + ((lq) ^ (lr & 7)) * 8]);
      bf16x8 k1 = *(const bf16x8*)(&Klds[buf][row * 64 + ((4 + lq) ^ (lr & 7)) * 8]);
      sf[ni] = __builtin_amdgcn_mfma_f32_16x16x32_bf16(qf0, k0, sf[ni], 0, 0, 0);
      sf[ni] = __builtin_amdgcn_mfma_f32_16x16x32_bf16(qf1, k1, sf[ni], 0, 0, 0);
    }
    if (kt == qt) {
      #pragma unroll
      for (int ni = 0; ni < 4; ++ni) {
        int col = ni * 16 + lr;
        #pragma unroll
        for (int r = 0; r < 4; ++r) {
          int row = wave * 16 + lq * 4 + r;
          if (col > row) sf[ni][r] = -1e30f;
        }
      }
    }
    // p = exp2(s); per-lane l accumulation; P -> wave-private LDS (A-layout)
    #pragma unroll
    for (int ni = 0; ni < 4; ++ni)
      #pragma unroll
      for (int r = 0; r < 4; ++r) {
        float p = exp2f(sf[ni][r]);
        sf[ni][r] = p;
        lsum[r] += p;
        Pl[wave][lq * 4 + r][ni * 16 + lr] = f2bf(p);
      }
    bf16x8 pa0 = *(const bf16x8*)(&Pl[wave][lr][lq * 8]);
    bf16x8 pa1 = *(const bf16x8*)(&Pl[wave][lr][32 + lq * 8]);
    #pragma unroll
    for (int ni = 0; ni < 4; ++ni) {
      int row = ni * 16 + lr;
      bf16x8 v0 = *(const bf16x8*)(&Vl[buf][row * 64 + ((lq) ^ (lr & 7)) * 8]);
      bf16x8 v1 = *(const bf16x8*)(&Vl[buf][row * 64 + ((4 + lq) ^ (lr & 7)) * 8]);
      of[ni] = __builtin_amdgcn_mfma_f32_16x16x32_bf16(pa0, v0, of[ni], 0, 0, 0);
      of[ni] = __builtin_amdgcn_mfma_f32_16x16x32_bf16(pa1, v1, of[ni], 0, 0, 0);
    }
  }
  #pragma unroll
  for (int r = 0; r < 4; ++r) {
    float l = lsum[r];
    l += __shfl_xor(l, 1);
    l += __shfl_xor(l, 2);
    l += __shfl_xor(l, 4);
    l += __shfl_xor(l, 8);
    float inv = 1.0f / l;
    int row = qt * 64 + wave * 16 + lq * 4 + r;
    u16* op = O + (size_t)(b * 2048 + row) * 1024 + hh * 64;
    #pragma unroll
    for (int ni = 0; ni < 4; ++ni)
      op[ni * 16 + lr] = f2bf(of[ni][r] * inv);
  }
}

extern "C" void kernel_launch(void* const* d_in, const int* in_sizes, int n_in,
                              void* d_out, int out_size, void* d_ws, size_t ws_size,
                              hipStream_t stream) {
  const float* x   = (const float*)d_in[0];
  const float* Wq  = (const float*)d_in[1];
  const float* Wk  = (const float*)d_in[2];
  const float* Wv  = (const float*)d_in[3];
  const float* Wp  = (const float*)d_in[4];
  const float* bp  = (const float*)d_in[5];
  const float* W1  = (const float*)d_in[6];
  const float* b1  = (const float*)d_in[7];
  const float* W2  = (const float*)d_in[8];
  const float* b2  = (const float*)d_in[9];
  const float* g1  = (const float*)d_in[10];
  const float* be1 = (const float*)d_in[11];
  const float* g2  = (const float*)d_in[12];
  const float* be2 = (const float*)d_in[13];
  float* out = (float*)d_out;

  u16* ws16   = (u16*)d_ws;
  u16* Wqkv_t = ws16;                      // 3,145,728
  u16* Wp_t   = Wqkv_t + 3145728;          // 1,048,576
  u16* W1_t   = Wp_t + 1048576;            // 4,194,304
  u16* W2_t   = W1_t + 4194304;            // 4,194,304
  u16* h      = W2_t + 4194304;            // 4,194,304 (LN1 out; reused for LN2)
  u16* QKV    = h + 4194304;               // 12,582,912
  u16* Obuf   = QKV + 12582912;            // 4,194,304
  u16* f      = QKV;                       // 16,777,216 (overlaps QKV+Obuf)
  float* x1   = (float*)(Obuf + 4194304);  // 4,194,304 floats
  u16* VT     = (u16*)(x1 + 4194304);      // 4,194,304

  const float qsc = 0.18033688f;  // 0.125 * log2(e), folded into Wq
  transpose_bf16<<<dim3(2, 32, 16), 256, 0, stream>>>(Wq, Wqkv_t, 1024, 64, 65536, 65536, 1024, qsc);
  transpose_bf16<<<dim3(2, 32, 16), 256, 0, stream>>>(Wk, Wqkv_t + 1048576, 1024, 64, 65536, 65536, 1024, 1.f);
  transpose_bf16<<<dim3(2, 32, 16), 256, 0, stream>>>(Wv, Wqkv_t + 2097152, 1024, 64, 65536, 65536, 1024, 1.f);
  transpose_bf16<<<dim3(32, 32, 1), 256, 0, stream>>>(Wp, Wp_t, 1024, 1024, 0, 0, 1024, 1.f);
  transpose_bf16<<<dim3(128, 32, 1), 256, 0, stream>>>(W1, W1_t, 1024, 4096, 0, 0, 1024, 1.f);
  transpose_bf16<<<dim3(32, 128, 1), 256, 0, stream>>>(W2, W2_t, 4096, 1024, 0, 0, 4096, 1.f);

  ln_bf16<<<4096, 256, 0, stream>>>(x, g1, be1, h);
  gemm_bf16<128, 128><<<dim3(24, 32), 256, 0, stream>>>(h, Wqkv_t, nullptr, nullptr,
                                                        nullptr, QKV, 4096, 3072, 1024, 0);
  vtrans<<<dim3(64, 16), 256, 0, stream>>>(QKV, VT);
  attn_mfma<<<dim3(32, 32), 256, 0, stream>>>(QKV, VT, Obuf);
  gemm_bf16<128, 64><<<dim3(16, 32), 256, 0, stream>>>(Obuf, Wp_t, bp, x,
                                                       x1, nullptr, 4096, 1024, 1024, 0);
  ln_bf16<<<4096, 256, 0, stream>>>(x1, g2, be2, h);
  gemm_bf16<128, 128><<<dim3(32, 32), 256, 0, stream>>>(h, W1_t, b1, nullptr,
                                                        nullptr, f, 4096, 4096, 1024, 1);
  gemm_bf16<128, 64><<<dim3(16, 32), 256, 0, stream>>>(f, W2_t, b2, x1,
                                                       out, nullptr, 4096, 1024, 4096, 0);
}

// Round 5
// 350.241 us; speedup vs baseline: 6.2842x; 1.1853x over previous
//
#include <hip/hip_runtime.h>
#include <math.h>
#include <stdint.h>

// B=2, T=2048, E=1024, H=16, HS=64. bf16 MFMA.
// Transposed MFMA formulation (operand swap) for packed stores; paired causal
// Q-tiles for perfect load balance; depth-2 prefetch dbuf GEMM.
typedef unsigned short u16;
typedef __attribute__((ext_vector_type(8))) short bf16x8;
typedef __attribute__((ext_vector_type(4))) float f32x4;

__device__ __forceinline__ u16 f2bf(float f) {
  unsigned int u = __float_as_uint(f);
  u += 0x7FFFu + ((u >> 16) & 1u);
  return (u16)(u >> 16);
}

// pack 2 floats -> 2 bf16 (round half-up) in one u32 via byte-perm
__device__ __forceinline__ unsigned pkbf(float a, float b) {
  unsigned ua = __float_as_uint(a) + 0x8000u;
  unsigned ub = __float_as_uint(b) + 0x8000u;
  return __builtin_amdgcn_perm(ub, ua, 0x07060302u);
}

// ---------- tiled transpose fp32 [batch][R][C] -> bf16 [batch][C][R], ×scale ----------
__global__ __launch_bounds__(256) void transpose_bf16(
    const float* __restrict__ src, u16* __restrict__ dst,
    int R, int C, long sbs, long dbs, int drs, float scale) {
  __shared__ float tile[32][33];
  int c0 = blockIdx.x * 32, r0 = blockIdx.y * 32;
  long sb = (long)blockIdx.z * sbs, db = (long)blockIdx.z * dbs;
  int tx = threadIdx.x & 31, ty = threadIdx.x >> 5;
  #pragma unroll
  for (int k = 0; k < 4; ++k)
    tile[ty + k * 8][tx] = src[sb + (long)(r0 + ty + k * 8) * C + c0 + tx];
  __syncthreads();
  #pragma unroll
  for (int k = 0; k < 4; ++k)
    dst[db + (long)(c0 + ty + k * 8) * drs + r0 + tx] =
        f2bf(tile[tx][ty + k * 8] * scale);
}

// ---------- V^T builder: QKV V-cols -> VT [h][d=64][4096] bf16 ----------
__global__ __launch_bounds__(256) void vtrans(
    const u16* __restrict__ QKV, u16* __restrict__ VT) {
  __shared__ u16 Tl[64][72];
  int bt = blockIdx.x, h = blockIdx.y;
  int t = threadIdx.x;
  int r = t >> 3, c0 = (t & 7) << 3;
  const u16* src = QKV + (size_t)(bt * 64 + r) * 3072 + 2048 + h * 64 + c0;
  #pragma unroll
  for (int half = 0; half < 2; ++half) {
    bf16x8 v = *(const bf16x8*)(src + (size_t)(half * 32) * 3072);
    #pragma unroll
    for (int e = 0; e < 8; ++e) Tl[r + half * 32][c0 + e] = (u16)v[e];
  }
  __syncthreads();
  #pragma unroll
  for (int half = 0; half < 2; ++half) {
    int d = (t >> 3) + half * 32, s0 = (t & 7) << 3;
    bf16x8 o;
    #pragma unroll
    for (int e = 0; e < 8; ++e) o[e] = (short)Tl[s0 + e][d];
    *(bf16x8*)(VT + (size_t)(h * 64 + d) * 4096 + bt * 64 + s0) = o;
  }
}

// ---------- LayerNorm rows of 1024, bf16 out ----------
__global__ __launch_bounds__(256) void ln_bf16(
    const float* __restrict__ x, const float* __restrict__ g,
    const float* __restrict__ b, u16* __restrict__ out) {
  int row = blockIdx.x;
  const float* xr = x + (size_t)row * 1024;
  int t = threadIdx.x;
  float4 v = *(const float4*)(xr + t * 4);
  float s = v.x + v.y + v.z + v.w;
  float q = v.x * v.x + v.y * v.y + v.z * v.z + v.w * v.w;
  #pragma unroll
  for (int off = 32; off >= 1; off >>= 1) {
    s += __shfl_xor(s, off);
    q += __shfl_xor(q, off);
  }
  __shared__ float ss[4], qq[4];
  int wid = t >> 6;
  if ((t & 63) == 0) { ss[wid] = s; qq[wid] = q; }
  __syncthreads();
  float st = ss[0] + ss[1] + ss[2] + ss[3];
  float qt = qq[0] + qq[1] + qq[2] + qq[3];
  float mean = st * (1.0f / 1024.0f);
  float var = qt * (1.0f / 1024.0f) - mean * mean;
  float rstd = rsqrtf(var + 1e-5f);
  float4 gv = *(const float4*)(g + t * 4);
  float4 bv = *(const float4*)(b + t * 4);
  uint2 st2;
  st2.x = pkbf((v.x - mean) * rstd * gv.x + bv.x, (v.y - mean) * rstd * gv.y + bv.y);
  st2.y = pkbf((v.z - mean) * rstd * gv.z + bv.z, (v.w - mean) * rstd * gv.w + bv.w);
  *(uint2*)(out + (size_t)row * 1024 + t * 4) = st2;
}

// ---------- pipelined bf16 MFMA GEMM (transposed acc): C = A[M,K] @ Bt[N,K]^T ----------
// BK=64, 256 threads (4 waves 2x2), dbuf LDS, depth-2 reg prefetch.
// MFMA operands swapped so lane holds 4 consecutive N-cols -> packed stores.
template <int BM, int BN>
__global__ __launch_bounds__(256) void gemm_bf16(
    const u16* __restrict__ A, const u16* __restrict__ Bt,
    const float* __restrict__ bias, const float* __restrict__ res,
    float* __restrict__ Cf, u16* __restrict__ Cb,
    int M, int N, int K, int relu) {
  constexpr int MI = BM / 32, NI = BN / 32;
  constexpr int ACH = BM / 32, BCH = BN / 32;  // 1KB chunks per wave
  __shared__ u16 As[2][BM * 64];
  __shared__ u16 Bs[2][BN * 64];
  int tid = threadIdx.x, wave = tid >> 6, lane = tid & 63;
  int wm = wave >> 1, wn = wave & 1;
  int lr = lane & 15, lq = lane >> 4;
  int lrow = lane >> 3, kblk = (lane & 7) ^ (lrow & 7);
  int bn = blockIdx.x * BN, bm = blockIdx.y * BM;
  f32x4 acc[MI][NI];
  #pragma unroll
  for (int i = 0; i < MI; ++i)
    #pragma unroll
    for (int j = 0; j < NI; ++j) acc[i][j] = f32x4{0.f, 0.f, 0.f, 0.f};

  const u16* ag[ACH];
  #pragma unroll
  for (int j = 0; j < ACH; ++j) {
    int c = wave * ACH + j;
    ag[j] = A + (size_t)(bm + c * 8 + lrow) * K + kblk * 8;
  }
  const u16* bg[BCH];
  #pragma unroll
  for (int j = 0; j < BCH; ++j) {
    int c = wave * BCH + j;
    bg[j] = Bt + (size_t)(bn + c * 8 + lrow) * K + kblk * 8;
  }

  bf16x8 ra0[ACH], ra1[ACH], rb0[BCH], rb1[BCH];
  #pragma unroll
  for (int j = 0; j < ACH; ++j) { ra0[j] = *(const bf16x8*)(ag[j]); ra1[j] = *(const bf16x8*)(ag[j] + 64); }
  #pragma unroll
  for (int j = 0; j < BCH; ++j) { rb0[j] = *(const bf16x8*)(bg[j]); rb1[j] = *(const bf16x8*)(bg[j] + 64); }

  int nIter = K >> 6;  // K is always a multiple of 128 here

#define GEMM_STEP(BUF, RA, RB, IT)                                                         \
  {                                                                                        \
    _Pragma("unroll") for (int j = 0; j < ACH; ++j)                                        \
        *(bf16x8*)(&As[BUF][(wave * ACH + j) * 512 + lane * 8]) = RA[j];                   \
    _Pragma("unroll") for (int j = 0; j < BCH; ++j)                                        \
        *(bf16x8*)(&Bs[BUF][(wave * BCH + j) * 512 + lane * 8]) = RB[j];                   \
    __syncthreads();                                                                       \
    if ((IT) + 2 < nIter) {                                                                \
      int k0 = ((IT) + 2) << 6;                                                            \
      _Pragma("unroll") for (int j = 0; j < ACH; ++j) RA[j] = *(const bf16x8*)(ag[j] + k0); \
      _Pragma("unroll") for (int j = 0; j < BCH; ++j) RB[j] = *(const bf16x8*)(bg[j] + k0); \
    }                                                                                      \
    _Pragma("unroll") for (int kk = 0; kk < 2; ++kk) {                                     \
      bf16x8 af[MI], bfr[NI];                                                              \
      _Pragma("unroll") for (int mi = 0; mi < MI; ++mi)                                    \
          af[mi] = *(const bf16x8*)(&As[BUF][(wm * (BM / 2) + mi * 16 + lr) * 64 +         \
                                             (((kk << 2) + lq) ^ (lr & 7)) * 8]);          \
      _Pragma("unroll") for (int ni = 0; ni < NI; ++ni)                                    \
          bfr[ni] = *(const bf16x8*)(&Bs[BUF][(wn * (BN / 2) + ni * 16 + lr) * 64 +        \
                                              (((kk << 2) + lq) ^ (lr & 7)) * 8]);         \
      _Pragma("unroll") for (int mi = 0; mi < MI; ++mi)                                    \
          _Pragma("unroll") for (int ni = 0; ni < NI; ++ni)                                \
              acc[mi][ni] = __builtin_amdgcn_mfma_f32_16x16x32_bf16(bfr[ni], af[mi],       \
                                                                    acc[mi][ni], 0, 0, 0); \
    }                                                                                      \
  }

  for (int it = 0; it < nIter; it += 2) {
    GEMM_STEP(0, ra0, rb0, it)
    GEMM_STEP(1, ra1, rb1, it + 1)
  }
#undef GEMM_STEP

  // epilogue: lane holds C[row = ..mi*16+lr][cols col0..col0+3] (4 consecutive N)
  #pragma unroll
  for (int mi = 0; mi < MI; ++mi) {
    int row = bm + wm * (BM / 2) + mi * 16 + lr;
    #pragma unroll
    for (int ni = 0; ni < NI; ++ni) {
      int col = bn + wn * (BN / 2) + ni * 16 + lq * 4;
      f32x4 v = acc[mi][ni];
      if (bias) {
        float4 bb = *(const float4*)(bias + col);
        v[0] += bb.x; v[1] += bb.y; v[2] += bb.z; v[3] += bb.w;
      }
      if (res) {
        float4 rv = *(const float4*)(res + (size_t)row * N + col);
        v[0] += rv.x; v[1] += rv.y; v[2] += rv.z; v[3] += rv.w;
      }
      if (relu) {
        #pragma unroll
        for (int e = 0; e < 4; ++e) v[e] = fmaxf(v[e], 0.f);
      }
      if (Cb) {
        uint2 w;
        w.x = pkbf(v[0], v[1]);
        w.y = pkbf(v[2], v[3]);
        *(uint2*)(Cb + (size_t)row * N + col) = w;
      } else {
        float4 o;
        o.x = v[0]; o.y = v[1]; o.z = v[2]; o.w = v[3];
        *(float4*)(Cf + (size_t)row * N + col) = o;
      }
    }
  }
}

// ---------- MFMA flash attention: transposed (S^T/O^T), paired Q-tiles ----------
// QKV bf16 [4096][3072] (Q pre-scaled by 0.125*log2e); VT bf16 [16][64][4096].
// Block handles Q-tiles qtA=i and qtB=31-i (constant 33 tiles of work).
__global__ __launch_bounds__(256) void attn_mfma(
    const u16* __restrict__ QKV, const u16* __restrict__ VT,
    u16* __restrict__ O) {
  __shared__ u16 Klds[2][64 * 64];
  __shared__ u16 Vl[2][64 * 64];
  __shared__ u16 Pl[4][16 * 72];
  int i = blockIdx.x;  // 0..15
  int qtA = i, qtB = 31 - i;
  int b = blockIdx.y >> 4, hh = blockIdx.y & 15;
  int tid = threadIdx.x, wave = tid >> 6, lane = tid & 63;
  int lr = lane & 15, lq = lane >> 4;
  int lrow = lane >> 3, kb = (lane & 7) ^ (lrow & 7);

  // Q fragments (B-operand of S^T = K·Q^T): lane holds Q[row=qr][e=lq*8..]
  const u16* qbase = QKV + (size_t)(b * 2048) * 3072 + hh * 64 + lq * 8;
  int qrA = qtA * 64 + wave * 16 + lr, qrB = qtB * 64 + wave * 16 + lr;
  bf16x8 qA0 = *(const bf16x8*)(qbase + (size_t)qrA * 3072);
  bf16x8 qA1 = *(const bf16x8*)(qbase + (size_t)qrA * 3072 + 32);
  bf16x8 qB0 = *(const bf16x8*)(qbase + (size_t)qrB * 3072);
  bf16x8 qB1 = *(const bf16x8*)(qbase + (size_t)qrB * 3072 + 32);

  f32x4 ofA[4], ofB[4];
  float lA = 0.f, lB = 0.f;
  #pragma unroll
  for (int d = 0; d < 4; ++d) {
    ofA[d] = f32x4{0.f, 0.f, 0.f, 0.f};
    ofB[d] = f32x4{0.f, 0.f, 0.f, 0.f};
  }

  const u16* kg[2];
  const u16* vg[2];
  #pragma unroll
  for (int j = 0; j < 2; ++j) {
    int c = wave * 2 + j;
    kg[j] = QKV + (size_t)(b * 2048 + c * 8 + lrow) * 3072 + 1024 + hh * 64 + kb * 8;
    vg[j] = VT + (size_t)(hh * 64 + c * 8 + lrow) * 4096 + b * 2048 + kb * 8;
  }
  bf16x8 rk[2], rv[2];
  #pragma unroll
  for (int j = 0; j < 2; ++j) {
    rk[j] = *(const bf16x8*)(kg[j]);
    rv[j] = *(const bf16x8*)(vg[j]);
  }

  // one Q-tile's compute for the staged K/V tile `buf` at step kt
#define ATTN_TILE(Q0, Q1, QT, OF, LSUM)                                                    \
  {                                                                                        \
    f32x4 sf[4];                                                                           \
    _Pragma("unroll") for (int ni = 0; ni < 4; ++ni) sf[ni] = f32x4{0.f, 0.f, 0.f, 0.f};   \
    _Pragma("unroll") for (int ni = 0; ni < 4; ++ni) {                                     \
      int rowk = ni * 16 + lr;                                                             \
      bf16x8 k0 = *(const bf16x8*)(&Klds[buf][rowk * 64 + ((lq) ^ (lr & 7)) * 8]);         \
      bf16x8 k1 = *(const bf16x8*)(&Klds[buf][rowk * 64 + ((4 + lq) ^ (lr & 7)) * 8]);     \
      sf[ni] = __builtin_amdgcn_mfma_f32_16x16x32_bf16(k0, Q0, sf[ni], 0, 0, 0);           \
      sf[ni] = __builtin_amdgcn_mfma_f32_16x16x32_bf16(k1, Q1, sf[ni], 0, 0, 0);           \
    }                                                                                      \
    if (kt == (QT)) {                                                                      \
      _Pragma("unroll") for (int ni = 0; ni < 4; ++ni)                                     \
          _Pragma("unroll") for (int r = 0; r < 4; ++r)                                    \
              if (ni * 16 + lq * 4 + r > wave * 16 + lr) sf[ni][r] = -1e30f;               \
    }                                                                                      \
    _Pragma("unroll") for (int ni = 0; ni < 4; ++ni) {                                     \
      float p0 = exp2f(sf[ni][0]), p1 = exp2f(sf[ni][1]);                                  \
      float p2 = exp2f(sf[ni][2]), p3 = exp2f(sf[ni][3]);                                  \
      LSUM += (p0 + p1) + (p2 + p3);                                                       \
      uint2 w;                                                                             \
      w.x = pkbf(p0, p1);                                                                  \
      w.y = pkbf(p2, p3);                                                                  \
      *(uint2*)(&Pl[wave][lr * 72 + ni * 16 + lq * 4]) = w;                                \
    }                                                                                      \
    bf16x8 pf0 = *(const bf16x8*)(&Pl[wave][lr * 72 + lq * 8]);                            \
    bf16x8 pf1 = *(const bf16x8*)(&Pl[wave][lr * 72 + 32 + lq * 8]);                       \
    _Pragma("unroll") for (int di = 0; di < 4; ++di) {                                     \
      int rowv = di * 16 + lr;                                                             \
      bf16x8 v0 = *(const bf16x8*)(&Vl[buf][rowv * 64 + ((lq) ^ (lr & 7)) * 8]);           \
      bf16x8 v1 = *(const bf16x8*)(&Vl[buf][rowv * 64 + ((4 + lq) ^ (lr & 7)) * 8]);       \
      OF[di] = __builtin_amdgcn_mfma_f32_16x16x32_bf16(v0, pf0, OF[di], 0, 0, 0);          \
      OF[di] = __builtin_amdgcn_mfma_f32_16x16x32_bf16(v1, pf1, OF[di], 0, 0, 0);          \
    }                                                                                      \
  }

  for (int kt = 0; kt <= qtB; ++kt) {
    int buf = kt & 1;
    #pragma unroll
    for (int j = 0; j < 2; ++j) {
      *(bf16x8*)(&Klds[buf][(wave * 2 + j) * 512 + lane * 8]) = rk[j];
      *(bf16x8*)(&Vl[buf][(wave * 2 + j) * 512 + lane * 8]) = rv[j];
    }
    __syncthreads();
    if (kt < qtB) {
      #pragma unroll
      for (int j = 0; j < 2; ++j) {
        rk[j] = *(const bf16x8*)(kg[j] + (size_t)(kt + 1) * 64 * 3072);
        rv[j] = *(const bf16x8*)(vg[j] + (kt + 1) * 64);
      }
    }
    ATTN_TILE(qB0, qB1, qtB, ofB, lB)
    if (kt <= qtA) ATTN_TILE(qA0, qA1, qtA, ofA, lA)
  }
#undef ATTN_TILE

  // deferred normalization; lane's 16 O^T values all share q = lr
  lB += __shfl_xor(lB, 16);
  lB += __shfl_xor(lB, 32);
  lA += __shfl_xor(lA, 16);
  lA += __shfl_xor(lA, 32);
  float invB = 1.0f / lB, invA = 1.0f / lA;
  u16* opB = O + (size_t)(b * 2048 + qtB * 64 + wave * 16 + lr) * 1024 + hh * 64;
  u16* opA = O + (size_t)(b * 2048 + qtA * 64 + wave * 16 + lr) * 1024 + hh * 64;
  #pragma unroll
  for (int di = 0; di < 4; ++di) {
    uint2 wB, wA;
    wB.x = pkbf(ofB[di][0] * invB, ofB[di][1] * invB);
    wB.y = pkbf(ofB[di][2] * invB, ofB[di][3] * invB);
    wA.x = pkbf(ofA[di][0] * invA, ofA[di][1] * invA);
    wA.y = pkbf(ofA[di][2] * invA, ofA[di][3] * invA);
    *(uint2*)(opB + di * 16 + lq * 4) = wB;
    *(uint2*)(opA + di * 16 + lq * 4) = wA;
  }
}

extern "C" void kernel_launch(void* const* d_in, const int* in_sizes, int n_in,
                              void* d_out, int out_size, void* d_ws, size_t ws_size,
                              hipStream_t stream) {
  const float* x   = (const float*)d_in[0];
  const float* Wq  = (const float*)d_in[1];
  const float* Wk  = (const float*)d_in[2];
  const float* Wv  = (const float*)d_in[3];
  const float* Wp  = (const float*)d_in[4];
  const float* bp  = (const float*)d_in[5];
  const float* W1  = (const float*)d_in[6];
  const float* b1  = (const float*)d_in[7];
  const float* W2  = (const float*)d_in[8];
  const float* b2  = (const float*)d_in[9];
  const float* g1  = (const float*)d_in[10];
  const float* be1 = (const float*)d_in[11];
  const float* g2  = (const float*)d_in[12];
  const float* be2 = (const float*)d_in[13];
  float* out = (float*)d_out;

  u16* ws16   = (u16*)d_ws;
  u16* Wqkv_t = ws16;                      // 3,145,728
  u16* Wp_t   = Wqkv_t + 3145728;          // 1,048,576
  u16* W1_t   = Wp_t + 1048576;            // 4,194,304
  u16* W2_t   = W1_t + 4194304;            // 4,194,304
  u16* h      = W2_t + 4194304;            // 4,194,304 (LN1 out; reused for LN2)
  u16* QKV    = h + 4194304;               // 12,582,912
  u16* Obuf   = QKV + 12582912;            // 4,194,304
  u16* f      = QKV;                       // 16,777,216 (overlaps QKV+Obuf)
  float* x1   = (float*)(Obuf + 4194304);  // 4,194,304 floats
  u16* VT     = (u16*)(x1 + 4194304);      // 4,194,304

  const float qsc = 0.18033688f;  // 0.125 * log2(e), folded into Wq
  transpose_bf16<<<dim3(2, 32, 16), 256, 0, stream>>>(Wq, Wqkv_t, 1024, 64, 65536, 65536, 1024, qsc);
  transpose_bf16<<<dim3(2, 32, 16), 256, 0, stream>>>(Wk, Wqkv_t + 1048576, 1024, 64, 65536, 65536, 1024, 1.f);
  transpose_bf16<<<dim3(2, 32, 16), 256, 0, stream>>>(Wv, Wqkv_t + 2097152, 1024, 64, 65536, 65536, 1024, 1.f);
  transpose_bf16<<<dim3(32, 32, 1), 256, 0, stream>>>(Wp, Wp_t, 1024, 1024, 0, 0, 1024, 1.f);
  transpose_bf16<<<dim3(128, 32, 1), 256, 0, stream>>>(W1, W1_t, 1024, 4096, 0, 0, 1024, 1.f);
  transpose_bf16<<<dim3(32, 128, 1), 256, 0, stream>>>(W2, W2_t, 4096, 1024, 0, 0, 4096, 1.f);

  ln_bf16<<<4096, 256, 0, stream>>>(x, g1, be1, h);
  gemm_bf16<128, 128><<<dim3(24, 32), 256, 0, stream>>>(h, Wqkv_t, nullptr, nullptr,
                                                        nullptr, QKV, 4096, 3072, 1024, 0);
  vtrans<<<dim3(64, 16), 256, 0, stream>>>(QKV, VT);
  attn_mfma<<<dim3(16, 32), 256, 0, stream>>>(QKV, VT, Obuf);
  gemm_bf16<128, 64><<<dim3(16, 32), 256, 0, stream>>>(Obuf, Wp_t, bp, x,
                                                       x1, nullptr, 4096, 1024, 1024, 0);
  ln_bf16<<<4096, 256, 0, stream>>>(x1, g2, be2, h);
  gemm_bf16<128, 128><<<dim3(32, 32), 256, 0, stream>>>(h, W1_t, b1, nullptr,
                                                        nullptr, f, 4096, 4096, 1024, 1);
  gemm_bf16<128, 64><<<dim3(16, 32), 256, 0, stream>>>(f, W2_t, b2, x1,
                                                       out, nullptr, 4096, 1024, 4096, 0);
}

// Round 6
// 347.474 us; speedup vs baseline: 6.3342x; 1.0080x over previous
//
#include <hip/hip_runtime.h>
#include <math.h>
#include <stdint.h>

// B=2, T=2048, E=1024, H=16, HS=64. bf16 MFMA.
// r6: CK-style lgkm-only barriers (prefetch loads stay in flight across
// barriers) + XCD-aware block swizzle for L2 locality.
typedef unsigned short u16;
typedef __attribute__((ext_vector_type(8))) short bf16x8;
typedef __attribute__((ext_vector_type(4))) float f32x4;

__device__ __forceinline__ u16 f2bf(float f) {
  unsigned int u = __float_as_uint(f);
  u += 0x7FFFu + ((u >> 16) & 1u);
  return (u16)(u >> 16);
}

// pack 2 floats -> 2 bf16 (round half-up) in one u32 via byte-perm
__device__ __forceinline__ unsigned pkbf(float a, float b) {
  unsigned ua = __float_as_uint(a) + 0x8000u;
  unsigned ub = __float_as_uint(b) + 0x8000u;
  return __builtin_amdgcn_perm(ub, ua, 0x07060302u);
}

// barrier that waits only LDS ops: global prefetch loads stay in flight.
__device__ __forceinline__ void lds_barrier() {
  asm volatile("s_waitcnt lgkmcnt(0)\n\ts_barrier" ::: "memory");
}

// ---------- tiled transpose fp32 [batch][R][C] -> bf16 [batch][C][R], ×scale ----------
__global__ __launch_bounds__(256) void transpose_bf16(
    const float* __restrict__ src, u16* __restrict__ dst,
    int R, int C, long sbs, long dbs, int drs, float scale) {
  __shared__ float tile[32][33];
  int c0 = blockIdx.x * 32, r0 = blockIdx.y * 32;
  long sb = (long)blockIdx.z * sbs, db = (long)blockIdx.z * dbs;
  int tx = threadIdx.x & 31, ty = threadIdx.x >> 5;
  #pragma unroll
  for (int k = 0; k < 4; ++k)
    tile[ty + k * 8][tx] = src[sb + (long)(r0 + ty + k * 8) * C + c0 + tx];
  __syncthreads();
  #pragma unroll
  for (int k = 0; k < 4; ++k)
    dst[db + (long)(c0 + ty + k * 8) * drs + r0 + tx] =
        f2bf(tile[tx][ty + k * 8] * scale);
}

// ---------- V^T builder: QKV V-cols -> VT [h][d=64][4096] bf16 ----------
__global__ __launch_bounds__(256) void vtrans(
    const u16* __restrict__ QKV, u16* __restrict__ VT) {
  __shared__ u16 Tl[64][72];
  int bt = blockIdx.x, h = blockIdx.y;
  int t = threadIdx.x;
  int r = t >> 3, c0 = (t & 7) << 3;
  const u16* src = QKV + (size_t)(bt * 64 + r) * 3072 + 2048 + h * 64 + c0;
  #pragma unroll
  for (int half = 0; half < 2; ++half) {
    bf16x8 v = *(const bf16x8*)(src + (size_t)(half * 32) * 3072);
    #pragma unroll
    for (int e = 0; e < 8; ++e) Tl[r + half * 32][c0 + e] = (u16)v[e];
  }
  __syncthreads();
  #pragma unroll
  for (int half = 0; half < 2; ++half) {
    int d = (t >> 3) + half * 32, s0 = (t & 7) << 3;
    bf16x8 o;
    #pragma unroll
    for (int e = 0; e < 8; ++e) o[e] = (short)Tl[s0 + e][d];
    *(bf16x8*)(VT + (size_t)(h * 64 + d) * 4096 + bt * 64 + s0) = o;
  }
}

// ---------- LayerNorm rows of 1024, bf16 out ----------
__global__ __launch_bounds__(256) void ln_bf16(
    const float* __restrict__ x, const float* __restrict__ g,
    const float* __restrict__ b, u16* __restrict__ out) {
  int row = blockIdx.x;
  const float* xr = x + (size_t)row * 1024;
  int t = threadIdx.x;
  float4 v = *(const float4*)(xr + t * 4);
  float s = v.x + v.y + v.z + v.w;
  float q = v.x * v.x + v.y * v.y + v.z * v.z + v.w * v.w;
  #pragma unroll
  for (int off = 32; off >= 1; off >>= 1) {
    s += __shfl_xor(s, off);
    q += __shfl_xor(q, off);
  }
  __shared__ float ss[4], qq[4];
  int wid = t >> 6;
  if ((t & 63) == 0) { ss[wid] = s; qq[wid] = q; }
  __syncthreads();
  float st = ss[0] + ss[1] + ss[2] + ss[3];
  float qt = qq[0] + qq[1] + qq[2] + qq[3];
  float mean = st * (1.0f / 1024.0f);
  float var = qt * (1.0f / 1024.0f) - mean * mean;
  float rstd = rsqrtf(var + 1e-5f);
  float4 gv = *(const float4*)(g + t * 4);
  float4 bv = *(const float4*)(b + t * 4);
  uint2 st2;
  st2.x = pkbf((v.x - mean) * rstd * gv.x + bv.x, (v.y - mean) * rstd * gv.y + bv.y);
  st2.y = pkbf((v.z - mean) * rstd * gv.z + bv.z, (v.w - mean) * rstd * gv.w + bv.w);
  *(uint2*)(out + (size_t)row * 1024 + t * 4) = st2;
}

// ---------- pipelined bf16 MFMA GEMM (transposed acc): C = A[M,K] @ Bt[N,K]^T ----------
// BK=64, 256 threads (4 waves 2x2), dbuf LDS, depth-2 reg prefetch,
// lgkm-only barriers, XCD-aware swizzle (assumes M/BM == 32).
template <int BM, int BN>
__global__ __launch_bounds__(256) void gemm_bf16(
    const u16* __restrict__ A, const u16* __restrict__ Bt,
    const float* __restrict__ bias, const float* __restrict__ res,
    float* __restrict__ Cf, u16* __restrict__ Cb,
    int M, int N, int K, int relu) {
  constexpr int MI = BM / 32, NI = BN / 32;
  constexpr int ACH = BM / 32, BCH = BN / 32;  // 1KB chunks per wave
  __shared__ u16 As[2][BM * 64];
  __shared__ u16 Bs[2][BN * 64];
  int tid = threadIdx.x, wave = tid >> 6, lane = tid & 63;
  int wm = wave >> 1, wn = wave & 1;
  int lr = lane & 15, lq = lane >> 4;
  int lrow = lane >> 3, kblk = (lane & 7) ^ (lrow & 7);
  // XCD-aware swizzle: blocks with the same (g&7) share an XCD; give each
  // XCD a contiguous 4-row-block A band (1 MB, L2-resident) and stream B.
  int g = blockIdx.x;
  int bm = ((((g & 7) << 2) | ((g >> 3) & 3))) * BM;
  int bn = (g >> 5) * BN;
  f32x4 acc[MI][NI];
  #pragma unroll
  for (int i = 0; i < MI; ++i)
    #pragma unroll
    for (int j = 0; j < NI; ++j) acc[i][j] = f32x4{0.f, 0.f, 0.f, 0.f};

  const u16* ag[ACH];
  #pragma unroll
  for (int j = 0; j < ACH; ++j) {
    int c = wave * ACH + j;
    ag[j] = A + (size_t)(bm + c * 8 + lrow) * K + kblk * 8;
  }
  const u16* bg[BCH];
  #pragma unroll
  for (int j = 0; j < BCH; ++j) {
    int c = wave * BCH + j;
    bg[j] = Bt + (size_t)(bn + c * 8 + lrow) * K + kblk * 8;
  }

  bf16x8 ra0[ACH], ra1[ACH], rb0[BCH], rb1[BCH];
  #pragma unroll
  for (int j = 0; j < ACH; ++j) { ra0[j] = *(const bf16x8*)(ag[j]); ra1[j] = *(const bf16x8*)(ag[j] + 64); }
  #pragma unroll
  for (int j = 0; j < BCH; ++j) { rb0[j] = *(const bf16x8*)(bg[j]); rb1[j] = *(const bf16x8*)(bg[j] + 64); }

  int nIter = K >> 6;  // K is always a multiple of 128 here

#define GEMM_STEP(BUF, RA, RB, IT)                                                         \
  {                                                                                        \
    _Pragma("unroll") for (int j = 0; j < ACH; ++j)                                        \
        *(bf16x8*)(&As[BUF][(wave * ACH + j) * 512 + lane * 8]) = RA[j];                   \
    _Pragma("unroll") for (int j = 0; j < BCH; ++j)                                        \
        *(bf16x8*)(&Bs[BUF][(wave * BCH + j) * 512 + lane * 8]) = RB[j];                   \
    lds_barrier();                                                                         \
    if ((IT) + 2 < nIter) {                                                                \
      int k0 = ((IT) + 2) << 6;                                                            \
      _Pragma("unroll") for (int j = 0; j < ACH; ++j) RA[j] = *(const bf16x8*)(ag[j] + k0); \
      _Pragma("unroll") for (int j = 0; j < BCH; ++j) RB[j] = *(const bf16x8*)(bg[j] + k0); \
    }                                                                                      \
    _Pragma("unroll") for (int kk = 0; kk < 2; ++kk) {                                     \
      bf16x8 af[MI], bfr[NI];                                                              \
      _Pragma("unroll") for (int mi = 0; mi < MI; ++mi)                                    \
          af[mi] = *(const bf16x8*)(&As[BUF][(wm * (BM / 2) + mi * 16 + lr) * 64 +         \
                                             (((kk << 2) + lq) ^ (lr & 7)) * 8]);          \
      _Pragma("unroll") for (int ni = 0; ni < NI; ++ni)                                    \
          bfr[ni] = *(const bf16x8*)(&Bs[BUF][(wn * (BN / 2) + ni * 16 + lr) * 64 +        \
                                              (((kk << 2) + lq) ^ (lr & 7)) * 8]);         \
      _Pragma("unroll") for (int mi = 0; mi < MI; ++mi)                                    \
          _Pragma("unroll") for (int ni = 0; ni < NI; ++ni)                                \
              acc[mi][ni] = __builtin_amdgcn_mfma_f32_16x16x32_bf16(bfr[ni], af[mi],       \
                                                                    acc[mi][ni], 0, 0, 0); \
    }                                                                                      \
    lds_barrier();                                                                         \
  }

  for (int it = 0; it < nIter; it += 2) {
    GEMM_STEP(0, ra0, rb0, it)
    GEMM_STEP(1, ra1, rb1, it + 1)
  }
#undef GEMM_STEP

  // epilogue: lane holds C[row = ..mi*16+lr][cols col0..col0+3] (4 consecutive N)
  #pragma unroll
  for (int mi = 0; mi < MI; ++mi) {
    int row = bm + wm * (BM / 2) + mi * 16 + lr;
    #pragma unroll
    for (int ni = 0; ni < NI; ++ni) {
      int col = bn + wn * (BN / 2) + ni * 16 + lq * 4;
      f32x4 v = acc[mi][ni];
      if (bias) {
        float4 bb = *(const float4*)(bias + col);
        v[0] += bb.x; v[1] += bb.y; v[2] += bb.z; v[3] += bb.w;
      }
      if (res) {
        float4 rv = *(const float4*)(res + (size_t)row * N + col);
        v[0] += rv.x; v[1] += rv.y; v[2] += rv.z; v[3] += rv.w;
      }
      if (relu) {
        #pragma unroll
        for (int e = 0; e < 4; ++e) v[e] = fmaxf(v[e], 0.f);
      }
      if (Cb) {
        uint2 w;
        w.x = pkbf(v[0], v[1]);
        w.y = pkbf(v[2], v[3]);
        *(uint2*)(Cb + (size_t)row * N + col) = w;
      } else {
        float4 o;
        o.x = v[0]; o.y = v[1]; o.z = v[2]; o.w = v[3];
        *(float4*)(Cf + (size_t)row * N + col) = o;
      }
    }
  }
}

// ---------- MFMA flash attention: transposed (S^T/O^T), paired Q-tiles ----------
// QKV bf16 [4096][3072] (Q pre-scaled by 0.125*log2e); VT bf16 [16][64][4096].
// Block handles Q-tiles qtA=i and qtB=31-i (constant 33 tiles of work).
__global__ __launch_bounds__(256) void attn_mfma(
    const u16* __restrict__ QKV, const u16* __restrict__ VT,
    u16* __restrict__ O) {
  __shared__ u16 Klds[2][64 * 64];
  __shared__ u16 Vl[2][64 * 64];
  __shared__ u16 Pl[4][16 * 72];
  int i = blockIdx.x;  // 0..15
  int qtA = i, qtB = 31 - i;
  int b = blockIdx.y >> 4, hh = blockIdx.y & 15;
  int tid = threadIdx.x, wave = tid >> 6, lane = tid & 63;
  int lr = lane & 15, lq = lane >> 4;
  int lrow = lane >> 3, kb = (lane & 7) ^ (lrow & 7);

  // Q fragments (B-operand of S^T = K·Q^T): lane holds Q[row=qr][e=lq*8..]
  const u16* qbase = QKV + (size_t)(b * 2048) * 3072 + hh * 64 + lq * 8;
  int qrA = qtA * 64 + wave * 16 + lr, qrB = qtB * 64 + wave * 16 + lr;
  bf16x8 qA0 = *(const bf16x8*)(qbase + (size_t)qrA * 3072);
  bf16x8 qA1 = *(const bf16x8*)(qbase + (size_t)qrA * 3072 + 32);
  bf16x8 qB0 = *(const bf16x8*)(qbase + (size_t)qrB * 3072);
  bf16x8 qB1 = *(const bf16x8*)(qbase + (size_t)qrB * 3072 + 32);

  f32x4 ofA[4], ofB[4];
  float lA = 0.f, lB = 0.f;
  #pragma unroll
  for (int d = 0; d < 4; ++d) {
    ofA[d] = f32x4{0.f, 0.f, 0.f, 0.f};
    ofB[d] = f32x4{0.f, 0.f, 0.f, 0.f};
  }

  const u16* kg[2];
  const u16* vg[2];
  #pragma unroll
  for (int j = 0; j < 2; ++j) {
    int c = wave * 2 + j;
    kg[j] = QKV + (size_t)(b * 2048 + c * 8 + lrow) * 3072 + 1024 + hh * 64 + kb * 8;
    vg[j] = VT + (size_t)(hh * 64 + c * 8 + lrow) * 4096 + b * 2048 + kb * 8;
  }
  bf16x8 rk[2], rv[2];
  #pragma unroll
  for (int j = 0; j < 2; ++j) {
    rk[j] = *(const bf16x8*)(kg[j]);
    rv[j] = *(const bf16x8*)(vg[j]);
  }

  // one Q-tile's compute for the staged K/V tile `buf` at step kt
#define ATTN_TILE(Q0, Q1, QT, OF, LSUM)                                                    \
  {                                                                                        \
    f32x4 sf[4];                                                                           \
    _Pragma("unroll") for (int ni = 0; ni < 4; ++ni) sf[ni] = f32x4{0.f, 0.f, 0.f, 0.f};   \
    _Pragma("unroll") for (int ni = 0; ni < 4; ++ni) {                                     \
      int rowk = ni * 16 + lr;                                                             \
      bf16x8 k0 = *(const bf16x8*)(&Klds[buf][rowk * 64 + ((lq) ^ (lr & 7)) * 8]);         \
      bf16x8 k1 = *(const bf16x8*)(&Klds[buf][rowk * 64 + ((4 + lq) ^ (lr & 7)) * 8]);     \
      sf[ni] = __builtin_amdgcn_mfma_f32_16x16x32_bf16(k0, Q0, sf[ni], 0, 0, 0);           \
      sf[ni] = __builtin_amdgcn_mfma_f32_16x16x32_bf16(k1, Q1, sf[ni], 0, 0, 0);           \
    }                                                                                      \
    if (kt == (QT)) {                                                                      \
      _Pragma("unroll") for (int ni = 0; ni < 4; ++ni)                                     \
          _Pragma("unroll") for (int r = 0; r < 4; ++r)                                    \
              if (ni * 16 + lq * 4 + r > wave * 16 + lr) sf[ni][r] = -1e30f;               \
    }                                                                                      \
    _Pragma("unroll") for (int ni = 0; ni < 4; ++ni) {                                     \
      float p0 = exp2f(sf[ni][0]), p1 = exp2f(sf[ni][1]);                                  \
      float p2 = exp2f(sf[ni][2]), p3 = exp2f(sf[ni][3]);                                  \
      LSUM += (p0 + p1) + (p2 + p3);                                                       \
      uint2 w;                                                                             \
      w.x = pkbf(p0, p1);                                                                  \
      w.y = pkbf(p2, p3);                                                                  \
      *(uint2*)(&Pl[wave][lr * 72 + ni * 16 + lq * 4]) = w;                                \
    }                                                                                      \
    bf16x8 pf0 = *(const bf16x8*)(&Pl[wave][lr * 72 + lq * 8]);                            \
    bf16x8 pf1 = *(const bf16x8*)(&Pl[wave][lr * 72 + 32 + lq * 8]);                       \
    _Pragma("unroll") for (int di = 0; di < 4; ++di) {                                     \
      int rowv = di * 16 + lr;                                                             \
      bf16x8 v0 = *(const bf16x8*)(&Vl[buf][rowv * 64 + ((lq) ^ (lr & 7)) * 8]);           \
      bf16x8 v1 = *(const bf16x8*)(&Vl[buf][rowv * 64 + ((4 + lq) ^ (lr & 7)) * 8]);       \
      OF[di] = __builtin_amdgcn_mfma_f32_16x16x32_bf16(v0, pf0, OF[di], 0, 0, 0);          \
      OF[di] = __builtin_amdgcn_mfma_f32_16x16x32_bf16(v1, pf1, OF[di], 0, 0, 0);          \
    }                                                                                      \
  }

  for (int kt = 0; kt <= qtB; ++kt) {
    int buf = kt & 1;
    #pragma unroll
    for (int j = 0; j < 2; ++j) {
      *(bf16x8*)(&Klds[buf][(wave * 2 + j) * 512 + lane * 8]) = rk[j];
      *(bf16x8*)(&Vl[buf][(wave * 2 + j) * 512 + lane * 8]) = rv[j];
    }
    lds_barrier();
    if (kt < qtB) {
      #pragma unroll
      for (int j = 0; j < 2; ++j) {
        rk[j] = *(const bf16x8*)(kg[j] + (size_t)(kt + 1) * 64 * 3072);
        rv[j] = *(const bf16x8*)(vg[j] + (kt + 1) * 64);
      }
    }
    ATTN_TILE(qB0, qB1, qtB, ofB, lB)
    if (kt <= qtA) ATTN_TILE(qA0, qA1, qtA, ofA, lA)
    lds_barrier();
  }
#undef ATTN_TILE

  // deferred normalization; lane's 16 O^T values all share q = lr
  lB += __shfl_xor(lB, 16);
  lB += __shfl_xor(lB, 32);
  lA += __shfl_xor(lA, 16);
  lA += __shfl_xor(lA, 32);
  float invB = 1.0f / lB, invA = 1.0f / lA;
  u16* opB = O + (size_t)(b * 2048 + qtB * 64 + wave * 16 + lr) * 1024 + hh * 64;
  u16* opA = O + (size_t)(b * 2048 + qtA * 64 + wave * 16 + lr) * 1024 + hh * 64;
  #pragma unroll
  for (int di = 0; di < 4; ++di) {
    uint2 wB, wA;
    wB.x = pkbf(ofB[di][0] * invB, ofB[di][1] * invB);
    wB.y = pkbf(ofB[di][2] * invB, ofB[di][3] * invB);
    wA.x = pkbf(ofA[di][0] * invA, ofA[di][1] * invA);
    wA.y = pkbf(ofA[di][2] * invA, ofA[di][3] * invA);
    *(uint2*)(opB + di * 16 + lq * 4) = wB;
    *(uint2*)(opA + di * 16 + lq * 4) = wA;
  }
}

extern "C" void kernel_launch(void* const* d_in, const int* in_sizes, int n_in,
                              void* d_out, int out_size, void* d_ws, size_t ws_size,
                              hipStream_t stream) {
  const float* x   = (const float*)d_in[0];
  const float* Wq  = (const float*)d_in[1];
  const float* Wk  = (const float*)d_in[2];
  const float* Wv  = (const float*)d_in[3];
  const float* Wp  = (const float*)d_in[4];
  const float* bp  = (const float*)d_in[5];
  const float* W1  = (const float*)d_in[6];
  const float* b1  = (const float*)d_in[7];
  const float* W2  = (const float*)d_in[8];
  const float* b2  = (const float*)d_in[9];
  const float* g1  = (const float*)d_in[10];
  const float* be1 = (const float*)d_in[11];
  const float* g2  = (const float*)d_in[12];
  const float* be2 = (const float*)d_in[13];
  float* out = (float*)d_out;

  u16* ws16   = (u16*)d_ws;
  u16* Wqkv_t = ws16;                      // 3,145,728
  u16* Wp_t   = Wqkv_t + 3145728;          // 1,048,576
  u16* W1_t   = Wp_t + 1048576;            // 4,194,304
  u16* W2_t   = W1_t + 4194304;            // 4,194,304
  u16* h      = W2_t + 4194304;            // 4,194,304 (LN1 out; reused for LN2)
  u16* QKV    = h + 4194304;               // 12,582,912
  u16* Obuf   = QKV + 12582912;            // 4,194,304
  u16* f      = QKV;                       // 16,777,216 (overlaps QKV+Obuf)
  float* x1   = (float*)(Obuf + 4194304);  // 4,194,304 floats
  u16* VT     = (u16*)(x1 + 4194304);      // 4,194,304

  const float qsc = 0.18033688f;  // 0.125 * log2(e), folded into Wq
  transpose_bf16<<<dim3(2, 32, 16), 256, 0, stream>>>(Wq, Wqkv_t, 1024, 64, 65536, 65536, 1024, qsc);
  transpose_bf16<<<dim3(2, 32, 16), 256, 0, stream>>>(Wk, Wqkv_t + 1048576, 1024, 64, 65536, 65536, 1024, 1.f);
  transpose_bf16<<<dim3(2, 32, 16), 256, 0, stream>>>(Wv, Wqkv_t + 2097152, 1024, 64, 65536, 65536, 1024, 1.f);
  transpose_bf16<<<dim3(32, 32, 1), 256, 0, stream>>>(Wp, Wp_t, 1024, 1024, 0, 0, 1024, 1.f);
  transpose_bf16<<<dim3(128, 32, 1), 256, 0, stream>>>(W1, W1_t, 1024, 4096, 0, 0, 1024, 1.f);
  transpose_bf16<<<dim3(32, 128, 1), 256, 0, stream>>>(W2, W2_t, 4096, 1024, 0, 0, 4096, 1.f);

  ln_bf16<<<4096, 256, 0, stream>>>(x, g1, be1, h);
  gemm_bf16<128, 128><<<768, 256, 0, stream>>>(h, Wqkv_t, nullptr, nullptr,
                                               nullptr, QKV, 4096, 3072, 1024, 0);
  vtrans<<<dim3(64, 16), 256, 0, stream>>>(QKV, VT);
  attn_mfma<<<dim3(16, 32), 256, 0, stream>>>(QKV, VT, Obuf);
  gemm_bf16<128, 64><<<512, 256, 0, stream>>>(Obuf, Wp_t, bp, x,
                                              x1, nullptr, 4096, 1024, 1024, 0);
  ln_bf16<<<4096, 256, 0, stream>>>(x1, g2, be2, h);
  gemm_bf16<128, 128><<<1024, 256, 0, stream>>>(h, W1_t, b1, nullptr,
                                                nullptr, f, 4096, 4096, 1024, 1);
  gemm_bf16<128, 64><<<512, 256, 0, stream>>>(f, W2_t, b2, x1,
                                              out, nullptr, 4096, 1024, 4096, 0);
}